// Round 1
// 656.842 us; speedup vs baseline: 1.2259x; 1.2259x over previous
//
#include <hip/hip_runtime.h>
#include <hip/hip_bf16.h>

#define S_N 100000
#define E_N 30000
#define K_N 1000
#define D_K 64
#define F_K 128
#define B_N 16384
#define NNZ_S 1600000
#define NNZ_E 480000
#define NNZ_K 32000
#define NNZ_TOT (NNZ_S + NNZ_E + NNZ_K)

// scan chunking: 2048 elements per block (256 threads x 8)
#define CH_S 49   // ceil(100000/2048)
#define CH_E 15   // ceil(30000/2048)
#define CH_K 1
#define CH_TOT (CH_S + CH_E + CH_K)

// 128-row buckets for the two-stage scatter
#define NB_S 782  // ceil(100000/128)
#define NB_E 235  // ceil(30000/128)
#define NB_K 8    // ceil(1000/128)
#define NB_TOT (NB_S + NB_E + NB_K)

// stage1 block-local binning: 4096 entries per block
#define CHUNK 4096
#define SB_S 391  // ceil(1600000/4096)
#define SB_E 118  // ceil(480000/4096)
#define SB_K 8    // ceil(32000/4096)
#define SB_TOT (SB_S + SB_E + SB_K)

typedef __attribute__((ext_vector_type(8))) short sh8;
typedef __attribute__((ext_vector_type(4))) float f4;

__device__ inline float b2f(ushort u) { return __uint_as_float((unsigned)u << 16); }
__device__ inline ushort f2b(float f) {
    unsigned u = __float_as_uint(f);
    return (ushort)((u + 0x7fffu + ((u >> 16) & 1u)) >> 16);
}

// ---------------------------------------------------------------- CSR build
__global__ void count_kernel(const int* __restrict__ sr, const int* __restrict__ er,
                             const int* __restrict__ kr,
                             int* cnt_s, int* cnt_e, int* cnt_k) {
    int i = blockIdx.x * 256 + threadIdx.x;
    if (i >= NNZ_TOT) return;
    if (i < NNZ_S) atomicAdd(&cnt_s[sr[i]], 1);
    else if (i < NNZ_S + NNZ_E) atomicAdd(&cnt_e[er[i - NNZ_S]], 1);
    else atomicAdd(&cnt_k[kr[i - NNZ_S - NNZ_E]], 1);
}

__device__ inline void seg_map(int b, const int* cnt_s, const int* cnt_e, const int* cnt_k,
                               const int** src, int* len, int* chunk, int* seg) {
    if (b < CH_S)            { *src = cnt_s; *len = S_N; *chunk = b;            *seg = 0; }
    else if (b < CH_S + CH_E){ *src = cnt_e; *len = E_N; *chunk = b - CH_S;     *seg = 1; }
    else                     { *src = cnt_k; *len = K_N; *chunk = 0;            *seg = 2; }
}

__global__ void scan_a(const int* cnt_s, const int* cnt_e, const int* cnt_k, int* partials) {
    const int* src; int len, chunk, seg;
    seg_map(blockIdx.x, cnt_s, cnt_e, cnt_k, &src, &len, &chunk, &seg);
    int base = chunk * 2048 + threadIdx.x * 8;
    int s = 0;
    for (int j = 0; j < 8; j++) { int idx = base + j; if (idx < len) s += src[idx]; }
    __shared__ int red[256];
    red[threadIdx.x] = s; __syncthreads();
    for (int off = 128; off > 0; off >>= 1) {
        if (threadIdx.x < off) red[threadIdx.x] += red[threadIdx.x + off];
        __syncthreads();
    }
    if (threadIdx.x == 0) partials[blockIdx.x] = red[0];
}

__global__ void scan_b(const int* partials, int* chunk_off, int* rp_s, int* rp_e, int* rp_k) {
    if (threadIdx.x == 0 && blockIdx.x == 0) {
        int acc = 0;
        for (int i = 0; i < CH_S; i++) { chunk_off[i] = acc; acc += partials[i]; }
        rp_s[S_N] = acc;
        acc = 0;
        for (int i = CH_S; i < CH_S + CH_E; i++) { chunk_off[i] = acc; acc += partials[i]; }
        rp_e[E_N] = acc;
        chunk_off[CH_S + CH_E] = 0;
        rp_k[K_N] = partials[CH_S + CH_E];
    }
}

__global__ void scan_c(const int* cnt_s, const int* cnt_e, const int* cnt_k,
                       const int* chunk_off,
                       int* rp_s, int* rp_e, int* rp_k) {
    const int* src; int len, chunk, seg;
    seg_map(blockIdx.x, cnt_s, cnt_e, cnt_k, &src, &len, &chunk, &seg);
    int* rp = (seg == 0) ? rp_s : (seg == 1) ? rp_e : rp_k;
    int t = threadIdx.x;
    int base = chunk * 2048 + t * 8;
    int v[8]; int s = 0;
    for (int j = 0; j < 8; j++) { int idx = base + j; v[j] = (idx < len) ? src[idx] : 0; s += v[j]; }
    __shared__ int sd[256];
    sd[t] = s; __syncthreads();
    for (int off = 1; off < 256; off <<= 1) {
        int x = (t >= off) ? sd[t - off] : 0;
        __syncthreads();
        sd[t] += x;
        __syncthreads();
    }
    int pre = sd[t] - s + chunk_off[blockIdx.x];
    for (int j = 0; j < 8; j++) {
        int idx = base + j;
        if (idx < len) { rp[idx] = pre; pre += v[j]; }
    }
}

// ---- stage 1 v2: block-local LDS binning.
__global__ void stage1_bin(const int* __restrict__ sr, const int* __restrict__ sc,
                           const float* __restrict__ sv,
                           const int* __restrict__ er, const int* __restrict__ ec,
                           const float* __restrict__ ev,
                           const int* __restrict__ kr, const int* __restrict__ kc,
                           const float* __restrict__ kv,
                           const int* __restrict__ rp_s, const int* __restrict__ rp_e,
                           const int* __restrict__ rp_k,
                           int* bcnt, int2* stg_s, int2* stg_e, int2* stg_k) {
    int blk = blockIdx.x;
    const int* rows; const int* cols; const float* vals; const int* rp;
    int2* stg; int boff, nnz, nb, lblk;
    if (blk < SB_S) {
        lblk = blk; rows = sr; cols = sc; vals = sv; rp = rp_s; stg = stg_s;
        boff = 0; nnz = NNZ_S; nb = NB_S;
    } else if (blk < SB_S + SB_E) {
        lblk = blk - SB_S; rows = er; cols = ec; vals = ev; rp = rp_e; stg = stg_e;
        boff = NB_S; nnz = NNZ_E; nb = NB_E;
    } else {
        lblk = blk - SB_S - SB_E; rows = kr; cols = kc; vals = kv; rp = rp_k; stg = stg_k;
        boff = NB_S + NB_E; nnz = NNZ_K; nb = NB_K;
    }
    __shared__ int hist[NB_S];
    __shared__ int wbase[NB_S];
    int t = threadIdx.x;
    for (int i = t; i < nb; i += 256) hist[i] = 0;
    __syncthreads();
    int start = lblk * CHUNK, end = min(start + CHUNK, nnz);
    for (int i = start + t; i < end; i += 256) atomicAdd(&hist[rows[i] >> 7], 1);
    __syncthreads();
    for (int i = t; i < nb; i += 256) {
        int h = hist[i];
        int b0 = h ? atomicAdd(&bcnt[boff + i], h) : 0;
        wbase[i] = rp[i << 7] + b0;
        hist[i] = 0;
    }
    __syncthreads();
    for (int i = start + t; i < end; i += 256) {
        int r = rows[i]; int b = r >> 7;
        int p = wbase[b] + atomicAdd(&hist[b], 1);
        stg[p] = make_int2(((r & 127) << 25) | cols[i], __float_as_int(vals[i]));
    }
}

// stage 2: block per bucket; LDS per-row cursors; coalesced read, windowed write
__global__ void stage2_place(const int* __restrict__ rp_s, const int2* __restrict__ stg_s,
                             int2* pr_s,
                             const int* __restrict__ rp_e, const int2* __restrict__ stg_e,
                             int2* pr_e,
                             const int* __restrict__ rp_k, const int2* __restrict__ stg_k,
                             int2* pr_k) {
    int b = blockIdx.x;
    const int* rp; const int2* stg; int2* pr; int len;
    if (b < NB_S) { rp = rp_s; stg = stg_s; pr = pr_s; len = S_N; }
    else if (b < NB_S + NB_E) { b -= NB_S; rp = rp_e; stg = stg_e; pr = pr_e; len = E_N; }
    else { b -= NB_S + NB_E; rp = rp_k; stg = stg_k; pr = pr_k; len = K_N; }
    int r0 = b << 7;
    int rows = min(128, len - r0);
    __shared__ int nx[128];
    int t = threadIdx.x;
    if (t < rows) nx[t] = rp[r0 + t];
    __syncthreads();
    int j0 = rp[r0], j1 = rp[r0 + rows];
    for (int j = j0 + t; j < j1; j += 256) {
        int2 e = stg[j];
        int r_rel = ((unsigned)e.x) >> 25;
        int col = e.x & 0x01FFFFFF;
        int p = atomicAdd(&nx[r_rel], 1);
        pr[p] = make_int2(col, e.y);
    }
}

// ------------------------------------------------ f32 -> bf16 convert (embs)
__global__ void convert_bf16(const float* __restrict__ a, const float* __restrict__ b,
                             const float* __restrict__ c,
                             ushort* oa, ushort* ob, ushort* oc) {
    const int NA = S_N * 64, NB = E_N * 64, NC = K_N * 64;
    int i = (blockIdx.x * 256 + threadIdx.x) * 4;
    const float* src; ushort* dst;
    if (i < NA) { src = a; dst = oa; }
    else if (i < NA + NB) { i -= NA; src = b; dst = ob; }
    else if (i < NA + NB + NC) { i -= NA + NB; src = c; dst = oc; }
    else return;
    float4 v = *(const float4*)&src[i];
    ushort4 o;
    o.x = f2b(v.x); o.y = f2b(v.y); o.z = f2b(v.z); o.w = f2b(v.w);
    *(ushort4*)&dst[i] = o;
}

// --------------------------------------------------------- convolution SpMM
// 16-lane group per row, lane owns features 4l..4l+3 (ushort4 = 8B gathers).
// One x-load instruction covers 4 nnz (one per group) = 512B wave-wide.
// f32 accumulate in original j-order -> bit-identical to the scalar version.
__device__ __forceinline__ void spmm_row_compute(
        const int* __restrict__ rp, const int2* __restrict__ pr,
        const ushort* __restrict__ x, int r, int l, float* a) {
    const ushort4* __restrict__ X4 = (const ushort4*)x;
    int j0 = rp[r], j1 = rp[r + 1];
    ushort4 self = X4[r * 16 + l];
    float a0 = 0.9f * b2f(self.x), a1 = 0.9f * b2f(self.y);
    float a2 = 0.9f * b2f(self.z), a3 = 0.9f * b2f(self.w);
    int j = j0;
    for (; j + 8 <= j1; j += 8) {
        int2 q0 = pr[j + 0], q1 = pr[j + 1], q2 = pr[j + 2], q3 = pr[j + 3];
        int2 q4 = pr[j + 4], q5 = pr[j + 5], q6 = pr[j + 6], q7 = pr[j + 7];
        ushort4 v0 = X4[q0.x * 16 + l];
        ushort4 v1 = X4[q1.x * 16 + l];
        ushort4 v2 = X4[q2.x * 16 + l];
        ushort4 v3 = X4[q3.x * 16 + l];
        ushort4 v4 = X4[q4.x * 16 + l];
        ushort4 v5 = X4[q5.x * 16 + l];
        ushort4 v6 = X4[q6.x * 16 + l];
        ushort4 v7 = X4[q7.x * 16 + l];
        float w0 = __int_as_float(q0.y), w1 = __int_as_float(q1.y);
        float w2 = __int_as_float(q2.y), w3 = __int_as_float(q3.y);
        float w4 = __int_as_float(q4.y), w5 = __int_as_float(q5.y);
        float w6 = __int_as_float(q6.y), w7 = __int_as_float(q7.y);
        a0 = fmaf(w0, b2f(v0.x), a0); a1 = fmaf(w0, b2f(v0.y), a1);
        a2 = fmaf(w0, b2f(v0.z), a2); a3 = fmaf(w0, b2f(v0.w), a3);
        a0 = fmaf(w1, b2f(v1.x), a0); a1 = fmaf(w1, b2f(v1.y), a1);
        a2 = fmaf(w1, b2f(v1.z), a2); a3 = fmaf(w1, b2f(v1.w), a3);
        a0 = fmaf(w2, b2f(v2.x), a0); a1 = fmaf(w2, b2f(v2.y), a1);
        a2 = fmaf(w2, b2f(v2.z), a2); a3 = fmaf(w2, b2f(v2.w), a3);
        a0 = fmaf(w3, b2f(v3.x), a0); a1 = fmaf(w3, b2f(v3.y), a1);
        a2 = fmaf(w3, b2f(v3.z), a2); a3 = fmaf(w3, b2f(v3.w), a3);
        a0 = fmaf(w4, b2f(v4.x), a0); a1 = fmaf(w4, b2f(v4.y), a1);
        a2 = fmaf(w4, b2f(v4.z), a2); a3 = fmaf(w4, b2f(v4.w), a3);
        a0 = fmaf(w5, b2f(v5.x), a0); a1 = fmaf(w5, b2f(v5.y), a1);
        a2 = fmaf(w5, b2f(v5.z), a2); a3 = fmaf(w5, b2f(v5.w), a3);
        a0 = fmaf(w6, b2f(v6.x), a0); a1 = fmaf(w6, b2f(v6.y), a1);
        a2 = fmaf(w6, b2f(v6.z), a2); a3 = fmaf(w6, b2f(v6.w), a3);
        a0 = fmaf(w7, b2f(v7.x), a0); a1 = fmaf(w7, b2f(v7.y), a1);
        a2 = fmaf(w7, b2f(v7.z), a2); a3 = fmaf(w7, b2f(v7.w), a3);
    }
    if (j + 4 <= j1) {
        int2 q0 = pr[j + 0], q1 = pr[j + 1], q2 = pr[j + 2], q3 = pr[j + 3];
        ushort4 v0 = X4[q0.x * 16 + l];
        ushort4 v1 = X4[q1.x * 16 + l];
        ushort4 v2 = X4[q2.x * 16 + l];
        ushort4 v3 = X4[q3.x * 16 + l];
        float w0 = __int_as_float(q0.y), w1 = __int_as_float(q1.y);
        float w2 = __int_as_float(q2.y), w3 = __int_as_float(q3.y);
        a0 = fmaf(w0, b2f(v0.x), a0); a1 = fmaf(w0, b2f(v0.y), a1);
        a2 = fmaf(w0, b2f(v0.z), a2); a3 = fmaf(w0, b2f(v0.w), a3);
        a0 = fmaf(w1, b2f(v1.x), a0); a1 = fmaf(w1, b2f(v1.y), a1);
        a2 = fmaf(w1, b2f(v1.z), a2); a3 = fmaf(w1, b2f(v1.w), a3);
        a0 = fmaf(w2, b2f(v2.x), a0); a1 = fmaf(w2, b2f(v2.y), a1);
        a2 = fmaf(w2, b2f(v2.z), a2); a3 = fmaf(w2, b2f(v2.w), a3);
        a0 = fmaf(w3, b2f(v3.x), a0); a1 = fmaf(w3, b2f(v3.y), a1);
        a2 = fmaf(w3, b2f(v3.z), a2); a3 = fmaf(w3, b2f(v3.w), a3);
        j += 4;
    }
    if (j < j1) {
        // predicated 4-wide tail: clamp indices, zero weights beyond j1
        int last = j1 - 1;
        int2 q0 = pr[j];
        int2 q1 = pr[min(j + 1, last)];
        int2 q2 = pr[min(j + 2, last)];
        int2 q3 = pr[min(j + 3, last)];
        ushort4 v0 = X4[q0.x * 16 + l];
        ushort4 v1 = X4[q1.x * 16 + l];
        ushort4 v2 = X4[q2.x * 16 + l];
        ushort4 v3 = X4[q3.x * 16 + l];
        float w0 = __int_as_float(q0.y);
        float w1 = (j + 1 <= last) ? __int_as_float(q1.y) : 0.f;
        float w2 = (j + 2 <= last) ? __int_as_float(q2.y) : 0.f;
        float w3 = (j + 3 <= last) ? __int_as_float(q3.y) : 0.f;
        a0 = fmaf(w0, b2f(v0.x), a0); a1 = fmaf(w0, b2f(v0.y), a1);
        a2 = fmaf(w0, b2f(v0.z), a2); a3 = fmaf(w0, b2f(v0.w), a3);
        a0 = fmaf(w1, b2f(v1.x), a0); a1 = fmaf(w1, b2f(v1.y), a1);
        a2 = fmaf(w1, b2f(v1.z), a2); a3 = fmaf(w1, b2f(v1.w), a3);
        a0 = fmaf(w2, b2f(v2.x), a0); a1 = fmaf(w2, b2f(v2.y), a1);
        a2 = fmaf(w2, b2f(v2.z), a2); a3 = fmaf(w2, b2f(v2.w), a3);
        a0 = fmaf(w3, b2f(v3.x), a0); a1 = fmaf(w3, b2f(v3.y), a1);
        a2 = fmaf(w3, b2f(v3.z), a2); a3 = fmaf(w3, b2f(v3.w), a3);
    }
    a[0] = a0; a[1] = a1; a[2] = a2; a[3] = a3;
}

// full-table spmm (layers 1,2): 16-lane group per row
__global__ void spmm_full(const int* __restrict__ rp_s, const int2* __restrict__ pr_s,
                          const ushort* __restrict__ xs, ushort* ys,
                          const int* __restrict__ rp_e, const int2* __restrict__ pr_e,
                          const ushort* __restrict__ xe, ushort* ye,
                          const int* __restrict__ rp_k, const int2* __restrict__ pr_k,
                          const ushort* __restrict__ xk, ushort* yk) {
    int w = (blockIdx.x * 256 + threadIdx.x) >> 4;
    int l = threadIdx.x & 15;
    const int* rp; const int2* pr; const ushort* x; ushort* y; int r;
    if (w < S_N) { rp = rp_s; pr = pr_s; x = xs; y = ys; r = w; }
    else if (w < S_N + E_N) { rp = rp_e; pr = pr_e; x = xe; y = ye; r = w - S_N; }
    else if (w < S_N + E_N + K_N) { rp = rp_k; pr = pr_k; x = xk; y = yk; r = w - S_N - E_N; }
    else return;
    float a[4];
    spmm_row_compute(rp, pr, x, r, l, a);
    ushort4 o;
    o.x = f2b(a[0]); o.y = f2b(a[1]); o.z = f2b(a[2]); o.w = f2b(a[3]);
    *(ushort4*)&y[r * 64 + l * 4] = o;
}

// layer-3 spmm: only batch rows for S/E (per batch element, dup ids OK since
// each group writes its own output row), full table for K.
__global__ void spmm_last(const int* __restrict__ sid, const int* __restrict__ eid,
                          const int* __restrict__ rp_s, const int2* __restrict__ pr_s,
                          const ushort* __restrict__ xs, ushort* c3s,
                          const int* __restrict__ rp_e, const int2* __restrict__ pr_e,
                          const ushort* __restrict__ xe, ushort* c3e,
                          const int* __restrict__ rp_k, const int2* __restrict__ pr_k,
                          const ushort* __restrict__ xk, ushort* yk) {
    int w = (blockIdx.x * 256 + threadIdx.x) >> 4;
    int l = threadIdx.x & 15;
    const int* rp; const int2* pr; const ushort* x; ushort* y; int r; int orow;
    if (w < B_N) { rp = rp_s; pr = pr_s; x = xs; y = c3s; r = sid[w]; orow = w; }
    else if (w < 2 * B_N) {
        int b = w - B_N;
        rp = rp_e; pr = pr_e; x = xe; y = c3e; r = eid[b]; orow = b;
    } else if (w < 2 * B_N + K_N) {
        r = w - 2 * B_N;
        rp = rp_k; pr = pr_k; x = xk; y = yk; orow = r;
    } else return;
    float a[4];
    spmm_row_compute(rp, pr, x, r, l, a);
    ushort4 o;
    o.x = f2b(a[0]); o.y = f2b(a[1]); o.z = f2b(a[2]); o.w = f2b(a[3]);
    *(ushort4*)&y[orow * 64 + l * 4] = o;
}

// ------------------------------------------------- batch accumulator gathers
// layer-0 init from f32 embeddings
__global__ void gather_init(const int* __restrict__ sid, const int* __restrict__ eid,
                            const float* __restrict__ src_s, const float* __restrict__ src_e,
                            const float* __restrict__ src_k,
                            float* bacc_s, float* bacc_e, float* kacc) {
    int i = blockIdx.x * 256 + threadIdx.x;
    const int BD = B_N * 64;
    if (i < BD) {
        int b = i >> 6, d = i & 63;
        bacc_s[i] = src_s[(long)sid[b] * 64 + d];
    } else if (i < 2 * BD) {
        int ii = i - BD; int b = ii >> 6, d = ii & 63;
        bacc_e[ii] = src_e[(long)eid[b] * 64 + d];
    } else if (i < 2 * BD + K_N * 64) {
        int ii = i - 2 * BD;
        kacc[ii] = src_k[ii];
    }
}

// layers 1..2 accumulate from bf16 conv outputs
__global__ void gather_accb(const int* __restrict__ sid, const int* __restrict__ eid,
                            const ushort* __restrict__ src_s, const ushort* __restrict__ src_e,
                            const ushort* __restrict__ src_k,
                            float* bacc_s, float* bacc_e, float* kacc) {
    int i = blockIdx.x * 256 + threadIdx.x;
    const int BD = B_N * 64;
    if (i < BD) {
        int b = i >> 6, d = i & 63;
        bacc_s[i] += b2f(src_s[(long)sid[b] * 64 + d]);
    } else if (i < 2 * BD) {
        int ii = i - BD; int b = ii >> 6, d = ii & 63;
        bacc_e[ii] += b2f(src_e[(long)eid[b] * 64 + d]);
    } else if (i < 2 * BD + K_N * 64) {
        int ii = i - 2 * BD;
        kacc[ii] += b2f(src_k[ii]);
    }
}

// --------------------------------------------- small dense layers (D=64 -> F=128)
// block: 2 rows x 128 cols; X = 0.25*(bacc + c3[b]); out = leaky(X@W + b) in bf16
__global__ void dense_mm(const float* __restrict__ bacc_s, const ushort* __restrict__ c3_s,
                         const float* __restrict__ bacc_e, const ushort* __restrict__ c3_e,
                         const float* __restrict__ W_stu, const float* __restrict__ b_stu,
                         const float* __restrict__ W_exer, const float* __restrict__ b_exer,
                         __hip_bfloat16* st_b, __hip_bfloat16* df_b) {
    int which = blockIdx.y;
    const float* bacc = which ? bacc_e : bacc_s;
    const ushort* c3 = which ? c3_e : c3_s;
    const float* W = which ? W_exer : W_stu;
    const float* bias = which ? b_exer : b_stu;
    __hip_bfloat16* out = which ? df_b : st_b;
    int r0 = blockIdx.x * 2;
    int t = threadIdx.x;
    __shared__ float X[2][64];
    if (t < 128) {
        int lr = t >> 6, d = t & 63; int b = r0 + lr;
        X[lr][d] = 0.25f * (bacc[(long)b * 64 + d] + b2f(c3[(long)b * 64 + d]));
    }
    __syncthreads();
    int lr = t >> 7, f = t & 127;
    float acc = bias[f];
    for (int d = 0; d < 64; d++) acc += X[lr][d] * W[d * 128 + f];
    acc = acc > 0.f ? acc : 0.1f * acc;
    out[(long)(r0 + lr) * 128 + f] = __float2bfloat16(acc);
}

// knowledge: rows padded to 1024; writes f32 to d_out and bf16 (zero-padded) to ws
__global__ void know_mm(const float* __restrict__ kacc, const ushort* __restrict__ cur3_k,
                        const float* __restrict__ W, const float* __restrict__ bias,
                        float* out_f32, __hip_bfloat16* kn_b) {
    int r0 = blockIdx.x * 2;
    int t = threadIdx.x;
    __shared__ float X[2][64];
    if (t < 128) {
        int lr = t >> 6, d = t & 63; int r = r0 + lr;
        X[lr][d] = (r < K_N) ? 0.25f * (kacc[r * 64 + d] + b2f(cur3_k[r * 64 + d])) : 0.f;
    }
    __syncthreads();
    int lr = t >> 7, f = t & 127; int r = r0 + lr;
    float acc = bias[f];
    for (int d = 0; d < 64; d++) acc += X[lr][d] * W[d * 128 + f];
    acc = acc > 0.f ? acc : 0.1f * acc;
    if (r < K_N) {
        out_f32[(long)r * 128 + f] = acc;
        kn_b[(long)r * 128 + f] = __float2bfloat16(acc);
    } else {
        kn_b[(long)r * 128 + f] = __float2bfloat16(0.f);
    }
}

// disc = sigmoid(0.25*(bacc_e+c3_e[b]) . W_disc + b_disc), one wave per row
__global__ void disc_kernel(const float* __restrict__ bacc_e, const ushort* __restrict__ c3_e,
                            const float* __restrict__ W_disc, const float* __restrict__ b_disc,
                            float* out) {
    int w = (blockIdx.x * 256 + threadIdx.x) >> 6;
    int d = threadIdx.x & 63;
    if (w >= B_N) return;
    float x = 0.25f * (bacc_e[(long)w * 64 + d] + b2f(c3_e[(long)w * 64 + d])) * W_disc[d];
    for (int off = 32; off > 0; off >>= 1) x += __shfl_down(x, off, 64);
    if (d == 0) {
        float z = x + b_disc[0];
        out[w] = 1.f / (1.f + expf(-z));
    }
}

__global__ void impact_kernel(const int* __restrict__ eid, const float* __restrict__ imp,
                              float* out) {
    int i = blockIdx.x * 256 + threadIdx.x;
    if (i >= B_N * 64) return;
    int b = i >> 6, d = i & 63;
    out[i] = imp[(long)eid[b] * 64 + d];
}

// --------------------------------------------- big GEMM: [B,128] @ [128,1024p]^T
// wave computes 32x32 (2x2 tiles of mfma_f32_16x16x32_bf16), block = 4 waves = 64x64
__global__ void big_mm(const __hip_bfloat16* __restrict__ st, const __hip_bfloat16* __restrict__ df,
                       const __hip_bfloat16* __restrict__ kn,
                       float* __restrict__ out0, float* __restrict__ out1) {
    const ushort* X = (const ushort*)(blockIdx.z ? df : st);
    const ushort* Kn = (const ushort*)kn;
    float* out = blockIdx.z ? out1 : out0;
    int wv = threadIdx.x >> 6;
    int lane = threadIdx.x & 63;
    int m_blk = blockIdx.y * 64 + (wv >> 1) * 32;
    int n_blk = blockIdx.x * 64 + (wv & 1) * 32;
    int q = lane >> 4, l16 = lane & 15;
    f4 acc00 = {0.f, 0.f, 0.f, 0.f}, acc01 = acc00, acc10 = acc00, acc11 = acc00;
    for (int s = 0; s < 4; s++) {
        int kofs = s * 32 + q * 8;
        sh8 a0 = *(const sh8*)&X[(long)(m_blk + l16) * 128 + kofs];
        sh8 a1 = *(const sh8*)&X[(long)(m_blk + 16 + l16) * 128 + kofs];
        sh8 b0 = *(const sh8*)&Kn[(long)(n_blk + l16) * 128 + kofs];
        sh8 b1 = *(const sh8*)&Kn[(long)(n_blk + 16 + l16) * 128 + kofs];
        acc00 = __builtin_amdgcn_mfma_f32_16x16x32_bf16(a0, b0, acc00, 0, 0, 0);
        acc01 = __builtin_amdgcn_mfma_f32_16x16x32_bf16(a0, b1, acc01, 0, 0, 0);
        acc10 = __builtin_amdgcn_mfma_f32_16x16x32_bf16(a1, b0, acc10, 0, 0, 0);
        acc11 = __builtin_amdgcn_mfma_f32_16x16x32_bf16(a1, b1, acc11, 0, 0, 0);
    }
    // C/D layout: col = lane&15, row = (lane>>4)*4 + reg
    for (int r = 0; r < 4; r++) {
        int row0 = m_blk + q * 4 + r;
        int row1 = m_blk + 16 + q * 4 + r;
        int col0 = n_blk + l16;
        int col1 = n_blk + 16 + l16;
        if (col0 < K_N) {
            out[(long)row0 * K_N + col0] = acc00[r];
            out[(long)row1 * K_N + col0] = acc10[r];
        }
        if (col1 < K_N) {
            out[(long)row0 * K_N + col1] = acc01[r];
            out[(long)row1 * K_N + col1] = acc11[r];
        }
    }
}

// ---------------------------------------------------------------------------
extern "C" void kernel_launch(void* const* d_in, const int* in_sizes, int n_in,
                              void* d_out, int out_size, void* d_ws, size_t ws_size,
                              hipStream_t stream) {
    const int* sid = (const int*)d_in[0];
    const int* eid = (const int*)d_in[1];
    // d_in[2] q_mask unused
    const float* stu_emb = (const float*)d_in[3];
    const float* exer_emb = (const float*)d_in[4];
    const float* know_emb = (const float*)d_in[5];
    const float* impact_emb = (const float*)d_in[6];
    const int* s_rows = (const int*)d_in[7];
    const int* s_cols = (const int*)d_in[8];
    const float* s_vals = (const float*)d_in[9];
    const int* e_rows = (const int*)d_in[10];
    const int* e_cols = (const int*)d_in[11];
    const float* e_vals = (const float*)d_in[12];
    const int* k_rows = (const int*)d_in[13];
    const int* k_cols = (const int*)d_in[14];
    const float* k_vals = (const float*)d_in[15];
    const float* W_stu = (const float*)d_in[16];
    const float* b_stu = (const float*)d_in[17];
    const float* W_exer = (const float*)d_in[18];
    const float* b_exer = (const float*)d_in[19];
    const float* W_know = (const float*)d_in[20];
    const float* b_know = (const float*)d_in[21];
    const float* W_disc = (const float*)d_in[22];
    const float* b_disc = (const float*)d_in[23];

    float* out = (float*)d_out;
    float* out_st = out;                       // [B,1000]
    float* out_df = out + 16384000;            // [B,1000]
    float* out_disc = out + 32768000;          // [B,1]
    float* out_kn = out + 32784384;            // [1000,128]
    float* out_imp = out + 32912384;           // [B,64]

    char* p = (char*)d_ws;
    auto alloc = [&](size_t bytes) -> char* {
        char* r = p;
        p += (bytes + 255) & ~(size_t)255;
        return r;
    };
    ushort* xb_s = (ushort*)alloc((size_t)S_N * 64 * 2);   // bf16 embeddings
    ushort* xb_e = (ushort*)alloc((size_t)E_N * 64 * 2);
    ushort* xb_k = (ushort*)alloc((size_t)K_N * 64 * 2);
    ushort* bufA_s = (ushort*)alloc((size_t)S_N * 64 * 2);
    ushort* bufB_s = (ushort*)alloc((size_t)S_N * 64 * 2);
    ushort* bufA_e = (ushort*)alloc((size_t)E_N * 64 * 2);
    ushort* bufB_e = (ushort*)alloc((size_t)E_N * 64 * 2);
    ushort* bufA_k = (ushort*)alloc((size_t)K_N * 64 * 2);
    ushort* bufB_k = (ushort*)alloc((size_t)K_N * 64 * 2);
    ushort* c3s = (ushort*)alloc((size_t)B_N * 64 * 2);    // layer-3 per-batch rows
    ushort* c3e = (ushort*)alloc((size_t)B_N * 64 * 2);
    float* bacc_s = (float*)alloc((size_t)B_N * 64 * 4);
    float* bacc_e = (float*)alloc((size_t)B_N * 64 * 4);
    float* kacc = (float*)alloc((size_t)K_N * 64 * 4);
    __hip_bfloat16* st_b = (__hip_bfloat16*)alloc((size_t)B_N * 128 * 2);
    __hip_bfloat16* df_b = (__hip_bfloat16*)alloc((size_t)B_N * 128 * 2);
    __hip_bfloat16* kn_b = (__hip_bfloat16*)alloc((size_t)1024 * 128 * 2);
    // counters: cnt_s/cnt_e/cnt_k + bucket counters, contiguous for one memset
    int* cnt_s = (int*)alloc((size_t)(S_N + E_N + K_N + NB_TOT) * 4);
    int* cnt_e = cnt_s + S_N;
    int* cnt_k = cnt_e + E_N;
    int* bcnt = cnt_k + K_N;
    int* rp_s = (int*)alloc((size_t)(S_N + 1) * 4);
    int* rp_e = (int*)alloc((size_t)(E_N + 1) * 4);
    int* rp_k = (int*)alloc((size_t)(K_N + 1) * 4);
    int2* stg_s = (int2*)alloc((size_t)NNZ_S * 8);
    int2* stg_e = (int2*)alloc((size_t)NNZ_E * 8);
    int2* stg_k = (int2*)alloc((size_t)NNZ_K * 8);
    int2* pr_s = (int2*)alloc((size_t)NNZ_S * 8);
    int2* pr_e = (int2*)alloc((size_t)NNZ_E * 8);
    int2* pr_k = (int2*)alloc((size_t)NNZ_K * 8);
    int* partials = (int*)alloc(CH_TOT * 4);
    int* chunk_off = (int*)alloc(CH_TOT * 4);

    // ---- CSR build
    hipMemsetAsync(cnt_s, 0, (size_t)(S_N + E_N + K_N + NB_TOT) * 4, stream);
    count_kernel<<<NNZ_TOT / 256, 256, 0, stream>>>(s_rows, e_rows, k_rows, cnt_s, cnt_e, cnt_k);
    scan_a<<<CH_TOT, 256, 0, stream>>>(cnt_s, cnt_e, cnt_k, partials);
    scan_b<<<1, 64, 0, stream>>>(partials, chunk_off, rp_s, rp_e, rp_k);
    scan_c<<<CH_TOT, 256, 0, stream>>>(cnt_s, cnt_e, cnt_k, chunk_off, rp_s, rp_e, rp_k);
    stage1_bin<<<SB_TOT, 256, 0, stream>>>(
        s_rows, s_cols, s_vals, e_rows, e_cols, e_vals, k_rows, k_cols, k_vals,
        rp_s, rp_e, rp_k, bcnt, stg_s, stg_e, stg_k);
    stage2_place<<<NB_TOT, 256, 0, stream>>>(rp_s, stg_s, pr_s,
                                             rp_e, stg_e, pr_e,
                                             rp_k, stg_k, pr_k);

    // ---- bf16 convert of embeddings (spmm inputs)
    const int conv_blocks = ((S_N + E_N + K_N) * 64 / 4 + 255) / 256;
    convert_bf16<<<conv_blocks, 256, 0, stream>>>(stu_emb, exer_emb, know_emb, xb_s, xb_e, xb_k);

    // ---- convolution: G1(emb f32), L1, G2(cur1), L2, G3(cur2), L3(batched)
    const int gather_blocks = (2 * B_N * 64 + K_N * 64) / 256;
    const int full_blocks = ((S_N + E_N + K_N) * 16 + 255) / 256;
    const int last_blocks = ((2 * B_N + K_N) * 16 + 255) / 256;
    gather_init<<<gather_blocks, 256, 0, stream>>>(sid, eid, stu_emb, exer_emb, know_emb,
                                                   bacc_s, bacc_e, kacc);
    spmm_full<<<full_blocks, 256, 0, stream>>>(rp_s, pr_s, xb_s, bufA_s,
                                               rp_e, pr_e, xb_e, bufA_e,
                                               rp_k, pr_k, xb_k, bufA_k);
    gather_accb<<<gather_blocks, 256, 0, stream>>>(sid, eid, bufA_s, bufA_e, bufA_k,
                                                   bacc_s, bacc_e, kacc);
    spmm_full<<<full_blocks, 256, 0, stream>>>(rp_s, pr_s, bufA_s, bufB_s,
                                               rp_e, pr_e, bufA_e, bufB_e,
                                               rp_k, pr_k, bufA_k, bufB_k);
    gather_accb<<<gather_blocks, 256, 0, stream>>>(sid, eid, bufB_s, bufB_e, bufB_k,
                                                   bacc_s, bacc_e, kacc);
    // layer 3: only the rows the batch needs for S/E; full table for K
    spmm_last<<<last_blocks, 256, 0, stream>>>(sid, eid,
                                               rp_s, pr_s, bufB_s, c3s,
                                               rp_e, pr_e, bufB_e, c3e,
                                               rp_k, pr_k, bufB_k, bufA_k);

    // ---- dense stage (folds last gather + /4 scale)
    dense_mm<<<dim3(B_N / 2, 2), 256, 0, stream>>>(bacc_s, c3s, bacc_e, c3e,
                                                   W_stu, b_stu, W_exer, b_exer, st_b, df_b);
    know_mm<<<512, 256, 0, stream>>>(kacc, bufA_k, W_know, b_know, out_kn, kn_b);
    disc_kernel<<<B_N / 4, 256, 0, stream>>>(bacc_e, c3e, W_disc, b_disc, out_disc);
    impact_kernel<<<B_N * 64 / 256, 256, 0, stream>>>(eid, impact_emb, out_imp);

    // ---- big GEMMs: [B,128] @ kn^T -> [B,1000], both in one kernel (z = 0/1)
    big_mm<<<dim3(16, B_N / 64, 2), 256, 0, stream>>>(st_b, df_b, kn_b, out_st, out_df);
}

// Round 2
// 570.557 us; speedup vs baseline: 1.4113x; 1.1512x over previous
//
#include <hip/hip_runtime.h>
#include <hip/hip_bf16.h>

#define S_N 100000
#define E_N 30000
#define K_N 1000
#define D_K 64
#define F_K 128
#define B_N 16384
#define NNZ_S 1600000
#define NNZ_E 480000
#define NNZ_K 32000
#define NNZ_TOT (NNZ_S + NNZ_E + NNZ_K)

// 128-row buckets for the two-stage scatter
#define NB_S 782  // ceil(100000/128)
#define NB_E 235  // ceil(30000/128)
#define NB_K 8    // ceil(1000/128)
#define NB_TOT (NB_S + NB_E + NB_K)

// stage1 block-local binning: 4096 entries per block
#define CHUNK 4096
#define SB_S 391  // ceil(1600000/4096)
#define SB_E 118  // ceil(480000/4096)
#define SB_K 8    // ceil(32000/4096)
#define SB_TOT (SB_S + SB_E + SB_K)

typedef __attribute__((ext_vector_type(8))) short sh8;
typedef __attribute__((ext_vector_type(4))) float f4;

__device__ inline float b2f(ushort u) { return __uint_as_float((unsigned)u << 16); }
__device__ inline ushort f2b(float f) {
    unsigned u = __float_as_uint(f);
    return (ushort)((u + 0x7fffu + ((u >> 16) & 1u)) >> 16);
}

// ---------------------------------------------------- bucket-level CSR build
// Per-ROW global atomics (2.1M device-scope RMWs ~= 67MB of HBM write traffic)
// replaced by per-BUCKET counts: LDS histogram -> ~310K global atomics total.
__global__ void bucket_count(const int* __restrict__ sr, const int* __restrict__ er,
                             const int* __restrict__ kr, int* bcnt_tot) {
    int blk = blockIdx.x;
    const int* rows; int boff, nnz, nb, lblk;
    if (blk < SB_S)            { lblk = blk;              rows = sr; boff = 0;           nnz = NNZ_S; nb = NB_S; }
    else if (blk < SB_S + SB_E){ lblk = blk - SB_S;       rows = er; boff = NB_S;        nnz = NNZ_E; nb = NB_E; }
    else                       { lblk = blk - SB_S - SB_E; rows = kr; boff = NB_S + NB_E; nnz = NNZ_K; nb = NB_K; }
    __shared__ int hist[NB_S];
    int t = threadIdx.x;
    for (int i = t; i < nb; i += 256) hist[i] = 0;
    __syncthreads();
    int start = lblk * CHUNK, end = min(start + CHUNK, nnz);
    for (int i = start + t; i < end; i += 256) atomicAdd(&hist[rows[i] >> 7], 1);
    __syncthreads();
    for (int i = t; i < nb; i += 256) {
        int h = hist[i];
        if (h) atomicAdd(&bcnt_tot[boff + i], h);
    }
}

// one block: exclusive scan of the 1025 bucket totals -> per-segment bases.
// segment start offsets in the concatenated scan are compile-time constants.
__global__ void bucket_scan(const int* __restrict__ bcnt_tot, int* bucket_base,
                            int* rp_s, int* rp_e, int* rp_k) {
    __shared__ int sd[256];
    int t = threadIdx.x;
    int v[5]; int s = 0;
    for (int j = 0; j < 5; j++) {
        int idx = t * 5 + j;
        v[j] = (idx < NB_TOT) ? bcnt_tot[idx] : 0;
        s += v[j];
    }
    sd[t] = s; __syncthreads();
    for (int off = 1; off < 256; off <<= 1) {
        int x = (t >= off) ? sd[t - off] : 0;
        __syncthreads();
        sd[t] += x;
        __syncthreads();
    }
    int pre = sd[t] - s;  // exclusive over the concatenated buckets
    for (int j = 0; j < 5; j++) {
        int idx = t * 5 + j;
        if (idx < NB_TOT) {
            int segoff = (idx < NB_S) ? 0 : (idx < NB_S + NB_E) ? NNZ_S : (NNZ_S + NNZ_E);
            bucket_base[idx] = pre - segoff;
            pre += v[j];
        }
    }
    if (t == 0) { rp_s[S_N] = NNZ_S; rp_e[E_N] = NNZ_E; rp_k[K_N] = NNZ_K; }
}

// ---- stage 1: block-local LDS binning into bucket windows
__global__ void stage1_bin(const int* __restrict__ sr, const int* __restrict__ sc,
                           const float* __restrict__ sv,
                           const int* __restrict__ er, const int* __restrict__ ec,
                           const float* __restrict__ ev,
                           const int* __restrict__ kr, const int* __restrict__ kc,
                           const float* __restrict__ kv,
                           const int* __restrict__ bucket_base,
                           int* rsv, int2* stg_s, int2* stg_e, int2* stg_k) {
    int blk = blockIdx.x;
    const int* rows; const int* cols; const float* vals;
    int2* stg; int boff, nnz, nb, lblk;
    if (blk < SB_S) {
        lblk = blk; rows = sr; cols = sc; vals = sv; stg = stg_s;
        boff = 0; nnz = NNZ_S; nb = NB_S;
    } else if (blk < SB_S + SB_E) {
        lblk = blk - SB_S; rows = er; cols = ec; vals = ev; stg = stg_e;
        boff = NB_S; nnz = NNZ_E; nb = NB_E;
    } else {
        lblk = blk - SB_S - SB_E; rows = kr; cols = kc; vals = kv; stg = stg_k;
        boff = NB_S + NB_E; nnz = NNZ_K; nb = NB_K;
    }
    __shared__ int hist[NB_S];
    __shared__ int wbase[NB_S];
    int t = threadIdx.x;
    for (int i = t; i < nb; i += 256) hist[i] = 0;
    __syncthreads();
    int start = lblk * CHUNK, end = min(start + CHUNK, nnz);
    for (int i = start + t; i < end; i += 256) atomicAdd(&hist[rows[i] >> 7], 1);
    __syncthreads();
    for (int i = t; i < nb; i += 256) {
        int h = hist[i];
        int b0 = h ? atomicAdd(&rsv[boff + i], h) : 0;
        wbase[i] = bucket_base[boff + i] + b0;
        hist[i] = 0;
    }
    __syncthreads();
    for (int i = start + t; i < end; i += 256) {
        int r = rows[i]; int b = r >> 7;
        int p = wbase[b] + atomicAdd(&hist[b], 1);
        stg[p] = make_int2(((r & 127) << 25) | cols[i], __float_as_int(vals[i]));
    }
}

// stage 2: block per bucket. Derive per-row counts in LDS from the staged
// entries (L2-resident re-read), LDS-scan -> write rp directly, then place.
__global__ void stage2_place(const int* __restrict__ bucket_base, const int* __restrict__ bcnt_tot,
                             const int2* __restrict__ stg_s, int2* pr_s, int* rp_s,
                             const int2* __restrict__ stg_e, int2* pr_e, int* rp_e,
                             const int2* __restrict__ stg_k, int2* pr_k, int* rp_k) {
    int gb = blockIdx.x;
    int b = gb;
    const int2* stg; int2* pr; int* rp; int len;
    if (b < NB_S) { stg = stg_s; pr = pr_s; rp = rp_s; len = S_N; }
    else if (b < NB_S + NB_E) { b -= NB_S; stg = stg_e; pr = pr_e; rp = rp_e; len = E_N; }
    else { b -= NB_S + NB_E; stg = stg_k; pr = pr_k; rp = rp_k; len = K_N; }
    int r0 = b << 7;
    int rows = min(128, len - r0);
    __shared__ int cnt[128];
    __shared__ int nx[128];
    int t = threadIdx.x;
    if (t < 128) cnt[t] = 0;
    __syncthreads();
    int j0 = bucket_base[gb], j1 = j0 + bcnt_tot[gb];
    for (int j = j0 + t; j < j1; j += 256)
        atomicAdd(&cnt[((unsigned)stg[j].x) >> 25], 1);
    __syncthreads();
    int my = (t < 128) ? cnt[t] : 0;
    for (int off = 1; off < 128; off <<= 1) {
        int y = (t < 128 && t >= off) ? cnt[t - off] : 0;
        __syncthreads();
        if (t < 128) cnt[t] += y;
        __syncthreads();
    }
    if (t < 128) {
        int ex = j0 + cnt[t] - my;   // exclusive prefix within bucket
        nx[t] = ex;
        if (t < rows) rp[r0 + t] = ex;
    }
    __syncthreads();
    for (int j = j0 + t; j < j1; j += 256) {
        int2 e = stg[j];
        int r_rel = ((unsigned)e.x) >> 25;
        int col = e.x & 0x01FFFFFF;
        int p = atomicAdd(&nx[r_rel], 1);
        pr[p] = make_int2(col, e.y);
    }
}

// ------------------------------------------------ f32 -> bf16 convert (embs)
__global__ void convert_bf16(const float* __restrict__ a, const float* __restrict__ b,
                             const float* __restrict__ c,
                             ushort* oa, ushort* ob, ushort* oc) {
    const int NA = S_N * 64, NB = E_N * 64, NC = K_N * 64;
    int i = (blockIdx.x * 256 + threadIdx.x) * 4;
    const float* src; ushort* dst;
    if (i < NA) { src = a; dst = oa; }
    else if (i < NA + NB) { i -= NA; src = b; dst = ob; }
    else if (i < NA + NB + NC) { i -= NA + NB; src = c; dst = oc; }
    else return;
    float4 v = *(const float4*)&src[i];
    ushort4 o;
    o.x = f2b(v.x); o.y = f2b(v.y); o.z = f2b(v.z); o.w = f2b(v.w);
    *(ushort4*)&dst[i] = o;
}

// --------------------------------------------------------- convolution SpMM
// 16-lane group per row, lane owns features 4l..4l+3 (ushort4 = 8B gathers).
__device__ __forceinline__ void spmm_row_compute(
        const int* __restrict__ rp, const int2* __restrict__ pr,
        const ushort* __restrict__ x, int r, int l, float* a) {
    const ushort4* __restrict__ X4 = (const ushort4*)x;
    int j0 = rp[r], j1 = rp[r + 1];
    ushort4 self = X4[r * 16 + l];
    float a0 = 0.9f * b2f(self.x), a1 = 0.9f * b2f(self.y);
    float a2 = 0.9f * b2f(self.z), a3 = 0.9f * b2f(self.w);
    int j = j0;
    for (; j + 8 <= j1; j += 8) {
        int2 q0 = pr[j + 0], q1 = pr[j + 1], q2 = pr[j + 2], q3 = pr[j + 3];
        int2 q4 = pr[j + 4], q5 = pr[j + 5], q6 = pr[j + 6], q7 = pr[j + 7];
        ushort4 v0 = X4[q0.x * 16 + l];
        ushort4 v1 = X4[q1.x * 16 + l];
        ushort4 v2 = X4[q2.x * 16 + l];
        ushort4 v3 = X4[q3.x * 16 + l];
        ushort4 v4 = X4[q4.x * 16 + l];
        ushort4 v5 = X4[q5.x * 16 + l];
        ushort4 v6 = X4[q6.x * 16 + l];
        ushort4 v7 = X4[q7.x * 16 + l];
        float w0 = __int_as_float(q0.y), w1 = __int_as_float(q1.y);
        float w2 = __int_as_float(q2.y), w3 = __int_as_float(q3.y);
        float w4 = __int_as_float(q4.y), w5 = __int_as_float(q5.y);
        float w6 = __int_as_float(q6.y), w7 = __int_as_float(q7.y);
        a0 = fmaf(w0, b2f(v0.x), a0); a1 = fmaf(w0, b2f(v0.y), a1);
        a2 = fmaf(w0, b2f(v0.z), a2); a3 = fmaf(w0, b2f(v0.w), a3);
        a0 = fmaf(w1, b2f(v1.x), a0); a1 = fmaf(w1, b2f(v1.y), a1);
        a2 = fmaf(w1, b2f(v1.z), a2); a3 = fmaf(w1, b2f(v1.w), a3);
        a0 = fmaf(w2, b2f(v2.x), a0); a1 = fmaf(w2, b2f(v2.y), a1);
        a2 = fmaf(w2, b2f(v2.z), a2); a3 = fmaf(w2, b2f(v2.w), a3);
        a0 = fmaf(w3, b2f(v3.x), a0); a1 = fmaf(w3, b2f(v3.y), a1);
        a2 = fmaf(w3, b2f(v3.z), a2); a3 = fmaf(w3, b2f(v3.w), a3);
        a0 = fmaf(w4, b2f(v4.x), a0); a1 = fmaf(w4, b2f(v4.y), a1);
        a2 = fmaf(w4, b2f(v4.z), a2); a3 = fmaf(w4, b2f(v4.w), a3);
        a0 = fmaf(w5, b2f(v5.x), a0); a1 = fmaf(w5, b2f(v5.y), a1);
        a2 = fmaf(w5, b2f(v5.z), a2); a3 = fmaf(w5, b2f(v5.w), a3);
        a0 = fmaf(w6, b2f(v6.x), a0); a1 = fmaf(w6, b2f(v6.y), a1);
        a2 = fmaf(w6, b2f(v6.z), a2); a3 = fmaf(w6, b2f(v6.w), a3);
        a0 = fmaf(w7, b2f(v7.x), a0); a1 = fmaf(w7, b2f(v7.y), a1);
        a2 = fmaf(w7, b2f(v7.z), a2); a3 = fmaf(w7, b2f(v7.w), a3);
    }
    if (j + 4 <= j1) {
        int2 q0 = pr[j + 0], q1 = pr[j + 1], q2 = pr[j + 2], q3 = pr[j + 3];
        ushort4 v0 = X4[q0.x * 16 + l];
        ushort4 v1 = X4[q1.x * 16 + l];
        ushort4 v2 = X4[q2.x * 16 + l];
        ushort4 v3 = X4[q3.x * 16 + l];
        float w0 = __int_as_float(q0.y), w1 = __int_as_float(q1.y);
        float w2 = __int_as_float(q2.y), w3 = __int_as_float(q3.y);
        a0 = fmaf(w0, b2f(v0.x), a0); a1 = fmaf(w0, b2f(v0.y), a1);
        a2 = fmaf(w0, b2f(v0.z), a2); a3 = fmaf(w0, b2f(v0.w), a3);
        a0 = fmaf(w1, b2f(v1.x), a0); a1 = fmaf(w1, b2f(v1.y), a1);
        a2 = fmaf(w1, b2f(v1.z), a2); a3 = fmaf(w1, b2f(v1.w), a3);
        a0 = fmaf(w2, b2f(v2.x), a0); a1 = fmaf(w2, b2f(v2.y), a1);
        a2 = fmaf(w2, b2f(v2.z), a2); a3 = fmaf(w2, b2f(v2.w), a3);
        a0 = fmaf(w3, b2f(v3.x), a0); a1 = fmaf(w3, b2f(v3.y), a1);
        a2 = fmaf(w3, b2f(v3.z), a2); a3 = fmaf(w3, b2f(v3.w), a3);
        j += 4;
    }
    if (j < j1) {
        int last = j1 - 1;
        int2 q0 = pr[j];
        int2 q1 = pr[min(j + 1, last)];
        int2 q2 = pr[min(j + 2, last)];
        int2 q3 = pr[min(j + 3, last)];
        ushort4 v0 = X4[q0.x * 16 + l];
        ushort4 v1 = X4[q1.x * 16 + l];
        ushort4 v2 = X4[q2.x * 16 + l];
        ushort4 v3 = X4[q3.x * 16 + l];
        float w0 = __int_as_float(q0.y);
        float w1 = (j + 1 <= last) ? __int_as_float(q1.y) : 0.f;
        float w2 = (j + 2 <= last) ? __int_as_float(q2.y) : 0.f;
        float w3 = (j + 3 <= last) ? __int_as_float(q3.y) : 0.f;
        a0 = fmaf(w0, b2f(v0.x), a0); a1 = fmaf(w0, b2f(v0.y), a1);
        a2 = fmaf(w0, b2f(v0.z), a2); a3 = fmaf(w0, b2f(v0.w), a3);
        a0 = fmaf(w1, b2f(v1.x), a0); a1 = fmaf(w1, b2f(v1.y), a1);
        a2 = fmaf(w1, b2f(v1.z), a2); a3 = fmaf(w1, b2f(v1.w), a3);
        a0 = fmaf(w2, b2f(v2.x), a0); a1 = fmaf(w2, b2f(v2.y), a1);
        a2 = fmaf(w2, b2f(v2.z), a2); a3 = fmaf(w2, b2f(v2.w), a3);
        a0 = fmaf(w3, b2f(v3.x), a0); a1 = fmaf(w3, b2f(v3.y), a1);
        a2 = fmaf(w3, b2f(v3.z), a2); a3 = fmaf(w3, b2f(v3.w), a3);
    }
    a[0] = a0; a[1] = a1; a[2] = a2; a[3] = a3;
}

// full-table spmm (layers 1,2): 16-lane group per row
__global__ void spmm_full(const int* __restrict__ rp_s, const int2* __restrict__ pr_s,
                          const ushort* __restrict__ xs, ushort* ys,
                          const int* __restrict__ rp_e, const int2* __restrict__ pr_e,
                          const ushort* __restrict__ xe, ushort* ye,
                          const int* __restrict__ rp_k, const int2* __restrict__ pr_k,
                          const ushort* __restrict__ xk, ushort* yk) {
    int w = (blockIdx.x * 256 + threadIdx.x) >> 4;
    int l = threadIdx.x & 15;
    const int* rp; const int2* pr; const ushort* x; ushort* y; int r;
    if (w < S_N) { rp = rp_s; pr = pr_s; x = xs; y = ys; r = w; }
    else if (w < S_N + E_N) { rp = rp_e; pr = pr_e; x = xe; y = ye; r = w - S_N; }
    else if (w < S_N + E_N + K_N) { rp = rp_k; pr = pr_k; x = xk; y = yk; r = w - S_N - E_N; }
    else return;
    float a[4];
    spmm_row_compute(rp, pr, x, r, l, a);
    ushort4 o;
    o.x = f2b(a[0]); o.y = f2b(a[1]); o.z = f2b(a[2]); o.w = f2b(a[3]);
    *(ushort4*)&y[r * 64 + l * 4] = o;
}

// layer-3 spmm: only batch rows for S/E, full table for K.
__global__ void spmm_last(const int* __restrict__ sid, const int* __restrict__ eid,
                          const int* __restrict__ rp_s, const int2* __restrict__ pr_s,
                          const ushort* __restrict__ xs, ushort* c3s,
                          const int* __restrict__ rp_e, const int2* __restrict__ pr_e,
                          const ushort* __restrict__ xe, ushort* c3e,
                          const int* __restrict__ rp_k, const int2* __restrict__ pr_k,
                          const ushort* __restrict__ xk, ushort* yk) {
    int w = (blockIdx.x * 256 + threadIdx.x) >> 4;
    int l = threadIdx.x & 15;
    const int* rp; const int2* pr; const ushort* x; ushort* y; int r; int orow;
    if (w < B_N) { rp = rp_s; pr = pr_s; x = xs; y = c3s; r = sid[w]; orow = w; }
    else if (w < 2 * B_N) {
        int b = w - B_N;
        rp = rp_e; pr = pr_e; x = xe; y = c3e; r = eid[b]; orow = b;
    } else if (w < 2 * B_N + K_N) {
        r = w - 2 * B_N;
        rp = rp_k; pr = pr_k; x = xk; y = yk; orow = r;
    } else return;
    float a[4];
    spmm_row_compute(rp, pr, x, r, l, a);
    ushort4 o;
    o.x = f2b(a[0]); o.y = f2b(a[1]); o.z = f2b(a[2]); o.w = f2b(a[3]);
    *(ushort4*)&y[orow * 64 + l * 4] = o;
}

// ------------------------------------------------- batch accumulator gathers
__global__ void gather_init(const int* __restrict__ sid, const int* __restrict__ eid,
                            const float* __restrict__ src_s, const float* __restrict__ src_e,
                            const float* __restrict__ src_k,
                            float* bacc_s, float* bacc_e, float* kacc) {
    int i = blockIdx.x * 256 + threadIdx.x;
    const int BD = B_N * 64;
    if (i < BD) {
        int b = i >> 6, d = i & 63;
        bacc_s[i] = src_s[(long)sid[b] * 64 + d];
    } else if (i < 2 * BD) {
        int ii = i - BD; int b = ii >> 6, d = ii & 63;
        bacc_e[ii] = src_e[(long)eid[b] * 64 + d];
    } else if (i < 2 * BD + K_N * 64) {
        int ii = i - 2 * BD;
        kacc[ii] = src_k[ii];
    }
}

__global__ void gather_accb(const int* __restrict__ sid, const int* __restrict__ eid,
                            const ushort* __restrict__ src_s, const ushort* __restrict__ src_e,
                            const ushort* __restrict__ src_k,
                            float* bacc_s, float* bacc_e, float* kacc) {
    int i = blockIdx.x * 256 + threadIdx.x;
    const int BD = B_N * 64;
    if (i < BD) {
        int b = i >> 6, d = i & 63;
        bacc_s[i] += b2f(src_s[(long)sid[b] * 64 + d]);
    } else if (i < 2 * BD) {
        int ii = i - BD; int b = ii >> 6, d = ii & 63;
        bacc_e[ii] += b2f(src_e[(long)eid[b] * 64 + d]);
    } else if (i < 2 * BD + K_N * 64) {
        int ii = i - 2 * BD;
        kacc[ii] += b2f(src_k[ii]);
    }
}

// --------------------------------------------- small dense layers (D=64 -> F=128)
__global__ void dense_mm(const float* __restrict__ bacc_s, const ushort* __restrict__ c3_s,
                         const float* __restrict__ bacc_e, const ushort* __restrict__ c3_e,
                         const float* __restrict__ W_stu, const float* __restrict__ b_stu,
                         const float* __restrict__ W_exer, const float* __restrict__ b_exer,
                         __hip_bfloat16* st_b, __hip_bfloat16* df_b) {
    int which = blockIdx.y;
    const float* bacc = which ? bacc_e : bacc_s;
    const ushort* c3 = which ? c3_e : c3_s;
    const float* W = which ? W_exer : W_stu;
    const float* bias = which ? b_exer : b_stu;
    __hip_bfloat16* out = which ? df_b : st_b;
    int r0 = blockIdx.x * 2;
    int t = threadIdx.x;
    __shared__ float X[2][64];
    if (t < 128) {
        int lr = t >> 6, d = t & 63; int b = r0 + lr;
        X[lr][d] = 0.25f * (bacc[(long)b * 64 + d] + b2f(c3[(long)b * 64 + d]));
    }
    __syncthreads();
    int lr = t >> 7, f = t & 127;
    float acc = bias[f];
    for (int d = 0; d < 64; d++) acc += X[lr][d] * W[d * 128 + f];
    acc = acc > 0.f ? acc : 0.1f * acc;
    out[(long)(r0 + lr) * 128 + f] = __float2bfloat16(acc);
}

__global__ void know_mm(const float* __restrict__ kacc, const ushort* __restrict__ cur3_k,
                        const float* __restrict__ W, const float* __restrict__ bias,
                        float* out_f32, __hip_bfloat16* kn_b) {
    int r0 = blockIdx.x * 2;
    int t = threadIdx.x;
    __shared__ float X[2][64];
    if (t < 128) {
        int lr = t >> 6, d = t & 63; int r = r0 + lr;
        X[lr][d] = (r < K_N) ? 0.25f * (kacc[r * 64 + d] + b2f(cur3_k[r * 64 + d])) : 0.f;
    }
    __syncthreads();
    int lr = t >> 7, f = t & 127; int r = r0 + lr;
    float acc = bias[f];
    for (int d = 0; d < 64; d++) acc += X[lr][d] * W[d * 128 + f];
    acc = acc > 0.f ? acc : 0.1f * acc;
    if (r < K_N) {
        out_f32[(long)r * 128 + f] = acc;
        kn_b[(long)r * 128 + f] = __float2bfloat16(acc);
    } else {
        kn_b[(long)r * 128 + f] = __float2bfloat16(0.f);
    }
}

__global__ void disc_kernel(const float* __restrict__ bacc_e, const ushort* __restrict__ c3_e,
                            const float* __restrict__ W_disc, const float* __restrict__ b_disc,
                            float* out) {
    int w = (blockIdx.x * 256 + threadIdx.x) >> 6;
    int d = threadIdx.x & 63;
    if (w >= B_N) return;
    float x = 0.25f * (bacc_e[(long)w * 64 + d] + b2f(c3_e[(long)w * 64 + d])) * W_disc[d];
    for (int off = 32; off > 0; off >>= 1) x += __shfl_down(x, off, 64);
    if (d == 0) {
        float z = x + b_disc[0];
        out[w] = 1.f / (1.f + expf(-z));
    }
}

__global__ void impact_kernel(const int* __restrict__ eid, const float* __restrict__ imp,
                              float* out) {
    int i = blockIdx.x * 256 + threadIdx.x;
    if (i >= B_N * 64) return;
    int b = i >> 6, d = i & 63;
    out[i] = imp[(long)eid[b] * 64 + d];
}

// --------------------------------------------- big GEMM: [B,128] @ [128,1024p]^T
__global__ void big_mm(const __hip_bfloat16* __restrict__ st, const __hip_bfloat16* __restrict__ df,
                       const __hip_bfloat16* __restrict__ kn,
                       float* __restrict__ out0, float* __restrict__ out1) {
    const ushort* X = (const ushort*)(blockIdx.z ? df : st);
    const ushort* Kn = (const ushort*)kn;
    float* out = blockIdx.z ? out1 : out0;
    int wv = threadIdx.x >> 6;
    int lane = threadIdx.x & 63;
    int m_blk = blockIdx.y * 64 + (wv >> 1) * 32;
    int n_blk = blockIdx.x * 64 + (wv & 1) * 32;
    int q = lane >> 4, l16 = lane & 15;
    f4 acc00 = {0.f, 0.f, 0.f, 0.f}, acc01 = acc00, acc10 = acc00, acc11 = acc00;
    for (int s = 0; s < 4; s++) {
        int kofs = s * 32 + q * 8;
        sh8 a0 = *(const sh8*)&X[(long)(m_blk + l16) * 128 + kofs];
        sh8 a1 = *(const sh8*)&X[(long)(m_blk + 16 + l16) * 128 + kofs];
        sh8 b0 = *(const sh8*)&Kn[(long)(n_blk + l16) * 128 + kofs];
        sh8 b1 = *(const sh8*)&Kn[(long)(n_blk + 16 + l16) * 128 + kofs];
        acc00 = __builtin_amdgcn_mfma_f32_16x16x32_bf16(a0, b0, acc00, 0, 0, 0);
        acc01 = __builtin_amdgcn_mfma_f32_16x16x32_bf16(a0, b1, acc01, 0, 0, 0);
        acc10 = __builtin_amdgcn_mfma_f32_16x16x32_bf16(a1, b0, acc10, 0, 0, 0);
        acc11 = __builtin_amdgcn_mfma_f32_16x16x32_bf16(a1, b1, acc11, 0, 0, 0);
    }
    for (int r = 0; r < 4; r++) {
        int row0 = m_blk + q * 4 + r;
        int row1 = m_blk + 16 + q * 4 + r;
        int col0 = n_blk + l16;
        int col1 = n_blk + 16 + l16;
        if (col0 < K_N) {
            out[(long)row0 * K_N + col0] = acc00[r];
            out[(long)row1 * K_N + col0] = acc10[r];
        }
        if (col1 < K_N) {
            out[(long)row0 * K_N + col1] = acc01[r];
            out[(long)row1 * K_N + col1] = acc11[r];
        }
    }
}

// ---------------------------------------------------------------------------
extern "C" void kernel_launch(void* const* d_in, const int* in_sizes, int n_in,
                              void* d_out, int out_size, void* d_ws, size_t ws_size,
                              hipStream_t stream) {
    const int* sid = (const int*)d_in[0];
    const int* eid = (const int*)d_in[1];
    // d_in[2] q_mask unused
    const float* stu_emb = (const float*)d_in[3];
    const float* exer_emb = (const float*)d_in[4];
    const float* know_emb = (const float*)d_in[5];
    const float* impact_emb = (const float*)d_in[6];
    const int* s_rows = (const int*)d_in[7];
    const int* s_cols = (const int*)d_in[8];
    const float* s_vals = (const float*)d_in[9];
    const int* e_rows = (const int*)d_in[10];
    const int* e_cols = (const int*)d_in[11];
    const float* e_vals = (const float*)d_in[12];
    const int* k_rows = (const int*)d_in[13];
    const int* k_cols = (const int*)d_in[14];
    const float* k_vals = (const float*)d_in[15];
    const float* W_stu = (const float*)d_in[16];
    const float* b_stu = (const float*)d_in[17];
    const float* W_exer = (const float*)d_in[18];
    const float* b_exer = (const float*)d_in[19];
    const float* W_know = (const float*)d_in[20];
    const float* b_know = (const float*)d_in[21];
    const float* W_disc = (const float*)d_in[22];
    const float* b_disc = (const float*)d_in[23];

    float* out = (float*)d_out;
    float* out_st = out;                       // [B,1000]
    float* out_df = out + 16384000;            // [B,1000]
    float* out_disc = out + 32768000;          // [B,1]
    float* out_kn = out + 32784384;            // [1000,128]
    float* out_imp = out + 32912384;           // [B,64]

    char* p = (char*)d_ws;
    auto alloc = [&](size_t bytes) -> char* {
        char* r = p;
        p += (bytes + 255) & ~(size_t)255;
        return r;
    };
    ushort* xb_s = (ushort*)alloc((size_t)S_N * 64 * 2);   // bf16 embeddings
    ushort* xb_e = (ushort*)alloc((size_t)E_N * 64 * 2);
    ushort* xb_k = (ushort*)alloc((size_t)K_N * 64 * 2);
    ushort* bufA_s = (ushort*)alloc((size_t)S_N * 64 * 2);
    ushort* bufB_s = (ushort*)alloc((size_t)S_N * 64 * 2);
    ushort* bufA_e = (ushort*)alloc((size_t)E_N * 64 * 2);
    ushort* bufB_e = (ushort*)alloc((size_t)E_N * 64 * 2);
    ushort* bufA_k = (ushort*)alloc((size_t)K_N * 64 * 2);
    ushort* bufB_k = (ushort*)alloc((size_t)K_N * 64 * 2);
    ushort* c3s = (ushort*)alloc((size_t)B_N * 64 * 2);    // layer-3 per-batch rows
    ushort* c3e = (ushort*)alloc((size_t)B_N * 64 * 2);
    float* bacc_s = (float*)alloc((size_t)B_N * 64 * 4);
    float* bacc_e = (float*)alloc((size_t)B_N * 64 * 4);
    float* kacc = (float*)alloc((size_t)K_N * 64 * 4);
    __hip_bfloat16* st_b = (__hip_bfloat16*)alloc((size_t)B_N * 128 * 2);
    __hip_bfloat16* df_b = (__hip_bfloat16*)alloc((size_t)B_N * 128 * 2);
    __hip_bfloat16* kn_b = (__hip_bfloat16*)alloc((size_t)1024 * 128 * 2);
    // bucket totals + reservation cursors (zeroed together), bucket bases
    int* bcnt_tot = (int*)alloc((size_t)2 * NB_TOT * 4);
    int* rsv = bcnt_tot + NB_TOT;
    int* bucket_base = (int*)alloc((size_t)NB_TOT * 4);
    int* rp_s = (int*)alloc((size_t)(S_N + 1) * 4);
    int* rp_e = (int*)alloc((size_t)(E_N + 1) * 4);
    int* rp_k = (int*)alloc((size_t)(K_N + 1) * 4);
    int2* stg_s = (int2*)alloc((size_t)NNZ_S * 8);
    int2* stg_e = (int2*)alloc((size_t)NNZ_E * 8);
    int2* stg_k = (int2*)alloc((size_t)NNZ_K * 8);
    int2* pr_s = (int2*)alloc((size_t)NNZ_S * 8);
    int2* pr_e = (int2*)alloc((size_t)NNZ_E * 8);
    int2* pr_k = (int2*)alloc((size_t)NNZ_K * 8);

    // ---- CSR build (bucket-granular: no per-row global atomics)
    hipMemsetAsync(bcnt_tot, 0, (size_t)2 * NB_TOT * 4, stream);
    bucket_count<<<SB_TOT, 256, 0, stream>>>(s_rows, e_rows, k_rows, bcnt_tot);
    bucket_scan<<<1, 256, 0, stream>>>(bcnt_tot, bucket_base, rp_s, rp_e, rp_k);
    stage1_bin<<<SB_TOT, 256, 0, stream>>>(
        s_rows, s_cols, s_vals, e_rows, e_cols, e_vals, k_rows, k_cols, k_vals,
        bucket_base, rsv, stg_s, stg_e, stg_k);
    stage2_place<<<NB_TOT, 256, 0, stream>>>(bucket_base, bcnt_tot,
                                             stg_s, pr_s, rp_s,
                                             stg_e, pr_e, rp_e,
                                             stg_k, pr_k, rp_k);

    // ---- bf16 convert of embeddings (spmm inputs)
    const int conv_blocks = ((S_N + E_N + K_N) * 64 / 4 + 255) / 256;
    convert_bf16<<<conv_blocks, 256, 0, stream>>>(stu_emb, exer_emb, know_emb, xb_s, xb_e, xb_k);

    // ---- convolution: G1(emb f32), L1, G2(cur1), L2, G3(cur2), L3(batched)
    const int gather_blocks = (2 * B_N * 64 + K_N * 64) / 256;
    const int full_blocks = ((S_N + E_N + K_N) * 16 + 255) / 256;
    const int last_blocks = ((2 * B_N + K_N) * 16 + 255) / 256;
    gather_init<<<gather_blocks, 256, 0, stream>>>(sid, eid, stu_emb, exer_emb, know_emb,
                                                   bacc_s, bacc_e, kacc);
    spmm_full<<<full_blocks, 256, 0, stream>>>(rp_s, pr_s, xb_s, bufA_s,
                                               rp_e, pr_e, xb_e, bufA_e,
                                               rp_k, pr_k, xb_k, bufA_k);
    gather_accb<<<gather_blocks, 256, 0, stream>>>(sid, eid, bufA_s, bufA_e, bufA_k,
                                                   bacc_s, bacc_e, kacc);
    spmm_full<<<full_blocks, 256, 0, stream>>>(rp_s, pr_s, bufA_s, bufB_s,
                                               rp_e, pr_e, bufA_e, bufB_e,
                                               rp_k, pr_k, bufA_k, bufB_k);
    gather_accb<<<gather_blocks, 256, 0, stream>>>(sid, eid, bufB_s, bufB_e, bufB_k,
                                                   bacc_s, bacc_e, kacc);
    // layer 3: only the rows the batch needs for S/E; full table for K
    spmm_last<<<last_blocks, 256, 0, stream>>>(sid, eid,
                                               rp_s, pr_s, bufB_s, c3s,
                                               rp_e, pr_e, bufB_e, c3e,
                                               rp_k, pr_k, bufB_k, bufA_k);

    // ---- dense stage (folds last gather + /4 scale)
    dense_mm<<<dim3(B_N / 2, 2), 256, 0, stream>>>(bacc_s, c3s, bacc_e, c3e,
                                                   W_stu, b_stu, W_exer, b_exer, st_b, df_b);
    know_mm<<<512, 256, 0, stream>>>(kacc, bufA_k, W_know, b_know, out_kn, kn_b);
    disc_kernel<<<B_N / 4, 256, 0, stream>>>(bacc_e, c3e, W_disc, b_disc, out_disc);
    impact_kernel<<<B_N * 64 / 256, 256, 0, stream>>>(eid, impact_emb, out_imp);

    // ---- big GEMMs: [B,128] @ kn^T -> [B,1000], both in one kernel (z = 0/1)
    big_mm<<<dim3(16, B_N / 64, 2), 256, 0, stream>>>(st_b, df_b, kn_b, out_st, out_df);
}

// Round 3
// 545.570 us; speedup vs baseline: 1.4760x; 1.0458x over previous
//
#include <hip/hip_runtime.h>
#include <hip/hip_bf16.h>

#define S_N 100000
#define E_N 30000
#define K_N 1000
#define D_K 64
#define F_K 128
#define B_N 16384
#define NNZ_S 1600000
#define NNZ_E 480000
#define NNZ_K 32000
#define NNZ_TOT (NNZ_S + NNZ_E + NNZ_K)

// 128-row buckets for the two-stage scatter
#define NB_S 782  // ceil(100000/128)
#define NB_E 235  // ceil(30000/128)
#define NB_K 8    // ceil(1000/128)
#define NB_TOT (NB_S + NB_E + NB_K)

// stage1 block-local binning: 4096 entries per block
#define CHUNK 4096
#define SB_S 391  // ceil(1600000/4096)
#define SB_E 118  // ceil(480000/4096)
#define SB_K 8    // ceil(32000/4096)
#define SB_TOT (SB_S + SB_E + SB_K)

// fused-kernel block ranges
#define NCONV 8188   // ceil(131000*64/4 / 256)
#define NGATH 8442   // (2*B_N*64 + K_N*64)/256
#define NIMP 4096    // B_N*64/256
#define FULLB 8188   // ceil(131000*16 / 256)
#define LASTB 2111   // ceil((2*B_N+K_N)*16 / 256)
#define NDENSE 16384 // (B_N/2)*2
#define NKNOW 512
#define NDISC 4096   // B_N/4

typedef __attribute__((ext_vector_type(8))) short sh8;
typedef __attribute__((ext_vector_type(4))) float f4;

__device__ inline float b2f(ushort u) { return __uint_as_float((unsigned)u << 16); }
__device__ inline ushort f2b(float f) {
    unsigned u = __float_as_uint(f);
    return (ushort)((u + 0x7fffu + ((u >> 16) & 1u)) >> 16);
}

// =============================================================== pre kernel
// fuses: convert_bf16 | gather_init | bucket_count | impact (all independent)
__global__ void pre_kernel(const float* __restrict__ stu_emb, const float* __restrict__ exer_emb,
                           const float* __restrict__ know_emb,
                           ushort* xb_s, ushort* xb_e, ushort* xb_k,
                           const int* __restrict__ sid, const int* __restrict__ eid,
                           float* bacc_s, float* bacc_e, float* kacc,
                           const int* __restrict__ sr, const int* __restrict__ er,
                           const int* __restrict__ kr, int* bcnt_tot,
                           const float* __restrict__ imp, float* out_imp) {
    int blk = blockIdx.x;
    int t = threadIdx.x;
    if (blk < NCONV) {
        // ---- f32 -> bf16 convert of the three embedding tables
        const int NA = S_N * 64, NB = E_N * 64, NC = K_N * 64;
        int i = (blk * 256 + t) * 4;
        const float* src; ushort* dst;
        if (i < NA) { src = stu_emb; dst = xb_s; }
        else if (i < NA + NB) { i -= NA; src = exer_emb; dst = xb_e; }
        else if (i < NA + NB + NC) { i -= NA + NB; src = know_emb; dst = xb_k; }
        else return;
        float4 v = *(const float4*)&src[i];
        ushort4 o;
        o.x = f2b(v.x); o.y = f2b(v.y); o.z = f2b(v.z); o.w = f2b(v.w);
        *(ushort4*)&dst[i] = o;
    } else if (blk < NCONV + NGATH) {
        // ---- layer-0 accumulator init from f32 embeddings
        int i = (blk - NCONV) * 256 + t;
        const int BD = B_N * 64;
        if (i < BD) {
            int b = i >> 6, d = i & 63;
            bacc_s[i] = stu_emb[(long)sid[b] * 64 + d];
        } else if (i < 2 * BD) {
            int ii = i - BD; int b = ii >> 6, d = ii & 63;
            bacc_e[ii] = exer_emb[(long)eid[b] * 64 + d];
        } else if (i < 2 * BD + K_N * 64) {
            int ii = i - 2 * BD;
            kacc[ii] = know_emb[ii];
        }
    } else if (blk < NCONV + NGATH + SB_TOT) {
        // ---- bucket-level histogram (LDS aggregate -> ~310K global atomics)
        int lb = blk - NCONV - NGATH;
        const int* rows; int boff, nnz, nb, lblk;
        if (lb < SB_S)            { lblk = lb;              rows = sr; boff = 0;           nnz = NNZ_S; nb = NB_S; }
        else if (lb < SB_S + SB_E){ lblk = lb - SB_S;       rows = er; boff = NB_S;        nnz = NNZ_E; nb = NB_E; }
        else                      { lblk = lb - SB_S - SB_E; rows = kr; boff = NB_S + NB_E; nnz = NNZ_K; nb = NB_K; }
        __shared__ int hist[NB_S];
        for (int i = t; i < nb; i += 256) hist[i] = 0;
        __syncthreads();
        int start = lblk * CHUNK, end = min(start + CHUNK, nnz);
        for (int i = start + t; i < end; i += 256) atomicAdd(&hist[rows[i] >> 7], 1);
        __syncthreads();
        for (int i = t; i < nb; i += 256) {
            int h = hist[i];
            if (h) atomicAdd(&bcnt_tot[boff + i], h);
        }
    } else {
        // ---- impact output gather
        int i = (blk - NCONV - NGATH - SB_TOT) * 256 + t;
        if (i >= B_N * 64) return;
        int b = i >> 6, d = i & 63;
        out_imp[i] = imp[(long)eid[b] * 64 + d];
    }
}

// ---- stage 1: block-local LDS binning into bucket windows.
// segment-local bucket bases computed inline (exclusive scan of bcnt_tot).
__global__ void stage1_bin(const int* __restrict__ sr, const int* __restrict__ sc,
                           const float* __restrict__ sv,
                           const int* __restrict__ er, const int* __restrict__ ec,
                           const float* __restrict__ ev,
                           const int* __restrict__ kr, const int* __restrict__ kc,
                           const float* __restrict__ kv,
                           const int* __restrict__ bcnt_tot,
                           int* rsv, int2* stg_s, int2* stg_e, int2* stg_k) {
    int blk = blockIdx.x;
    const int* rows; const int* cols; const float* vals;
    int2* stg; int boff, nnz, nb, lblk;
    if (blk < SB_S) {
        lblk = blk; rows = sr; cols = sc; vals = sv; stg = stg_s;
        boff = 0; nnz = NNZ_S; nb = NB_S;
    } else if (blk < SB_S + SB_E) {
        lblk = blk - SB_S; rows = er; cols = ec; vals = ev; stg = stg_e;
        boff = NB_S; nnz = NNZ_E; nb = NB_E;
    } else {
        lblk = blk - SB_S - SB_E; rows = kr; cols = kc; vals = kv; stg = stg_k;
        boff = NB_S + NB_E; nnz = NNZ_K; nb = NB_K;
    }
    __shared__ int hist[NB_S];
    __shared__ int wbase[NB_S];
    __shared__ int base_l[NB_S];
    __shared__ int sc_s[256];
    int t = threadIdx.x;
    // segment-local exclusive scan of bucket counts (<=782 values)
    int lv[4]; int ls = 0;
    for (int j = 0; j < 4; j++) {
        int idx = t * 4 + j;
        lv[j] = (idx < nb) ? bcnt_tot[boff + idx] : 0;
        ls += lv[j];
    }
    sc_s[t] = ls; __syncthreads();
    for (int off = 1; off < 256; off <<= 1) {
        int x = (t >= off) ? sc_s[t - off] : 0;
        __syncthreads();
        sc_s[t] += x;
        __syncthreads();
    }
    int pre = sc_s[t] - ls;
    for (int j = 0; j < 4; j++) {
        int idx = t * 4 + j;
        if (idx < nb) { base_l[idx] = pre; pre += lv[j]; }
    }
    for (int i = t; i < nb; i += 256) hist[i] = 0;
    __syncthreads();
    int start = lblk * CHUNK, end = min(start + CHUNK, nnz);
    for (int i = start + t; i < end; i += 256) atomicAdd(&hist[rows[i] >> 7], 1);
    __syncthreads();
    for (int i = t; i < nb; i += 256) {
        int h = hist[i];
        int b0 = h ? atomicAdd(&rsv[boff + i], h) : 0;
        wbase[i] = base_l[i] + b0;
        hist[i] = 0;
    }
    __syncthreads();
    for (int i = start + t; i < end; i += 256) {
        int r = rows[i]; int b = r >> 7;
        int p = wbase[b] + atomicAdd(&hist[b], 1);
        stg[p] = make_int2(((r & 127) << 25) | cols[i], __float_as_int(vals[i]));
    }
}

// stage 2: block per bucket. Inline prefix (sum of prior buckets in segment),
// per-row counts from staged entries, LDS-scan -> write rp, then place.
__global__ void stage2_place(const int* __restrict__ bcnt_tot,
                             const int2* __restrict__ stg_s, int2* pr_s, int* rp_s,
                             const int2* __restrict__ stg_e, int2* pr_e, int* rp_e,
                             const int2* __restrict__ stg_k, int2* pr_k, int* rp_k) {
    int gb = blockIdx.x;
    int b = gb;
    const int2* stg; int2* pr; int* rp; int len, segbase, segnnz;
    if (b < NB_S) { stg = stg_s; pr = pr_s; rp = rp_s; len = S_N; segbase = 0; segnnz = NNZ_S; }
    else if (b < NB_S + NB_E) { b -= NB_S; stg = stg_e; pr = pr_e; rp = rp_e; len = E_N; segbase = NB_S; segnnz = NNZ_E; }
    else { b -= NB_S + NB_E; stg = stg_k; pr = pr_k; rp = rp_k; len = K_N; segbase = NB_S + NB_E; segnnz = NNZ_K; }
    int r0 = b << 7;
    int rows = min(128, len - r0);
    __shared__ int cnt[128];
    __shared__ int nx[128];
    __shared__ int red[256];
    int t = threadIdx.x;
    // segment-local prefix: sum bcnt_tot[segbase .. segbase+b)
    int s = 0;
    for (int i = t; i < b; i += 256) s += bcnt_tot[segbase + i];
    red[t] = s;
    if (t < 128) cnt[t] = 0;
    __syncthreads();
    for (int off = 128; off > 0; off >>= 1) {
        if (t < off) red[t] += red[t + off];
        __syncthreads();
    }
    int j0 = red[0];
    int j1 = j0 + bcnt_tot[segbase + b];
    if (b == 0 && t == 0) rp[len] = segnnz;
    for (int j = j0 + t; j < j1; j += 256)
        atomicAdd(&cnt[((unsigned)stg[j].x) >> 25], 1);
    __syncthreads();
    int my = (t < 128) ? cnt[t] : 0;
    for (int off = 1; off < 128; off <<= 1) {
        int y = (t < 128 && t >= off) ? cnt[t - off] : 0;
        __syncthreads();
        if (t < 128) cnt[t] += y;
        __syncthreads();
    }
    if (t < 128) {
        int ex = j0 + cnt[t] - my;   // exclusive prefix within bucket
        nx[t] = ex;
        if (t < rows) rp[r0 + t] = ex;
    }
    __syncthreads();
    for (int j = j0 + t; j < j1; j += 256) {
        int2 e = stg[j];
        int r_rel = ((unsigned)e.x) >> 25;
        int col = e.x & 0x01FFFFFF;
        int p = atomicAdd(&nx[r_rel], 1);
        pr[p] = make_int2(col, e.y);
    }
}

// --------------------------------------------------------- convolution SpMM
// 16-lane group per row, lane owns features 4l..4l+3 (ushort4 = 8B gathers).
__device__ __forceinline__ void spmm_row_compute(
        const int* __restrict__ rp, const int2* __restrict__ pr,
        const ushort* __restrict__ x, int r, int l, float* a) {
    const ushort4* __restrict__ X4 = (const ushort4*)x;
    int j0 = rp[r], j1 = rp[r + 1];
    ushort4 self = X4[r * 16 + l];
    float a0 = 0.9f * b2f(self.x), a1 = 0.9f * b2f(self.y);
    float a2 = 0.9f * b2f(self.z), a3 = 0.9f * b2f(self.w);
    int j = j0;
    for (; j + 8 <= j1; j += 8) {
        int2 q0 = pr[j + 0], q1 = pr[j + 1], q2 = pr[j + 2], q3 = pr[j + 3];
        int2 q4 = pr[j + 4], q5 = pr[j + 5], q6 = pr[j + 6], q7 = pr[j + 7];
        ushort4 v0 = X4[q0.x * 16 + l];
        ushort4 v1 = X4[q1.x * 16 + l];
        ushort4 v2 = X4[q2.x * 16 + l];
        ushort4 v3 = X4[q3.x * 16 + l];
        ushort4 v4 = X4[q4.x * 16 + l];
        ushort4 v5 = X4[q5.x * 16 + l];
        ushort4 v6 = X4[q6.x * 16 + l];
        ushort4 v7 = X4[q7.x * 16 + l];
        float w0 = __int_as_float(q0.y), w1 = __int_as_float(q1.y);
        float w2 = __int_as_float(q2.y), w3 = __int_as_float(q3.y);
        float w4 = __int_as_float(q4.y), w5 = __int_as_float(q5.y);
        float w6 = __int_as_float(q6.y), w7 = __int_as_float(q7.y);
        a0 = fmaf(w0, b2f(v0.x), a0); a1 = fmaf(w0, b2f(v0.y), a1);
        a2 = fmaf(w0, b2f(v0.z), a2); a3 = fmaf(w0, b2f(v0.w), a3);
        a0 = fmaf(w1, b2f(v1.x), a0); a1 = fmaf(w1, b2f(v1.y), a1);
        a2 = fmaf(w1, b2f(v1.z), a2); a3 = fmaf(w1, b2f(v1.w), a3);
        a0 = fmaf(w2, b2f(v2.x), a0); a1 = fmaf(w2, b2f(v2.y), a1);
        a2 = fmaf(w2, b2f(v2.z), a2); a3 = fmaf(w2, b2f(v2.w), a3);
        a0 = fmaf(w3, b2f(v3.x), a0); a1 = fmaf(w3, b2f(v3.y), a1);
        a2 = fmaf(w3, b2f(v3.z), a2); a3 = fmaf(w3, b2f(v3.w), a3);
        a0 = fmaf(w4, b2f(v4.x), a0); a1 = fmaf(w4, b2f(v4.y), a1);
        a2 = fmaf(w4, b2f(v4.z), a2); a3 = fmaf(w4, b2f(v4.w), a3);
        a0 = fmaf(w5, b2f(v5.x), a0); a1 = fmaf(w5, b2f(v5.y), a1);
        a2 = fmaf(w5, b2f(v5.z), a2); a3 = fmaf(w5, b2f(v5.w), a3);
        a0 = fmaf(w6, b2f(v6.x), a0); a1 = fmaf(w6, b2f(v6.y), a1);
        a2 = fmaf(w6, b2f(v6.z), a2); a3 = fmaf(w6, b2f(v6.w), a3);
        a0 = fmaf(w7, b2f(v7.x), a0); a1 = fmaf(w7, b2f(v7.y), a1);
        a2 = fmaf(w7, b2f(v7.z), a2); a3 = fmaf(w7, b2f(v7.w), a3);
    }
    if (j + 4 <= j1) {
        int2 q0 = pr[j + 0], q1 = pr[j + 1], q2 = pr[j + 2], q3 = pr[j + 3];
        ushort4 v0 = X4[q0.x * 16 + l];
        ushort4 v1 = X4[q1.x * 16 + l];
        ushort4 v2 = X4[q2.x * 16 + l];
        ushort4 v3 = X4[q3.x * 16 + l];
        float w0 = __int_as_float(q0.y), w1 = __int_as_float(q1.y);
        float w2 = __int_as_float(q2.y), w3 = __int_as_float(q3.y);
        a0 = fmaf(w0, b2f(v0.x), a0); a1 = fmaf(w0, b2f(v0.y), a1);
        a2 = fmaf(w0, b2f(v0.z), a2); a3 = fmaf(w0, b2f(v0.w), a3);
        a0 = fmaf(w1, b2f(v1.x), a0); a1 = fmaf(w1, b2f(v1.y), a1);
        a2 = fmaf(w1, b2f(v1.z), a2); a3 = fmaf(w1, b2f(v1.w), a3);
        a0 = fmaf(w2, b2f(v2.x), a0); a1 = fmaf(w2, b2f(v2.y), a1);
        a2 = fmaf(w2, b2f(v2.z), a2); a3 = fmaf(w2, b2f(v2.w), a3);
        a0 = fmaf(w3, b2f(v3.x), a0); a1 = fmaf(w3, b2f(v3.y), a1);
        a2 = fmaf(w3, b2f(v3.z), a2); a3 = fmaf(w3, b2f(v3.w), a3);
        j += 4;
    }
    if (j < j1) {
        int last = j1 - 1;
        int2 q0 = pr[j];
        int2 q1 = pr[min(j + 1, last)];
        int2 q2 = pr[min(j + 2, last)];
        int2 q3 = pr[min(j + 3, last)];
        ushort4 v0 = X4[q0.x * 16 + l];
        ushort4 v1 = X4[q1.x * 16 + l];
        ushort4 v2 = X4[q2.x * 16 + l];
        ushort4 v3 = X4[q3.x * 16 + l];
        float w0 = __int_as_float(q0.y);
        float w1 = (j + 1 <= last) ? __int_as_float(q1.y) : 0.f;
        float w2 = (j + 2 <= last) ? __int_as_float(q2.y) : 0.f;
        float w3 = (j + 3 <= last) ? __int_as_float(q3.y) : 0.f;
        a0 = fmaf(w0, b2f(v0.x), a0); a1 = fmaf(w0, b2f(v0.y), a1);
        a2 = fmaf(w0, b2f(v0.z), a2); a3 = fmaf(w0, b2f(v0.w), a3);
        a0 = fmaf(w1, b2f(v1.x), a0); a1 = fmaf(w1, b2f(v1.y), a1);
        a2 = fmaf(w1, b2f(v1.z), a2); a3 = fmaf(w1, b2f(v1.w), a3);
        a0 = fmaf(w2, b2f(v2.x), a0); a1 = fmaf(w2, b2f(v2.y), a1);
        a2 = fmaf(w2, b2f(v2.z), a2); a3 = fmaf(w2, b2f(v2.w), a3);
        a0 = fmaf(w3, b2f(v3.x), a0); a1 = fmaf(w3, b2f(v3.y), a1);
        a2 = fmaf(w3, b2f(v3.z), a2); a3 = fmaf(w3, b2f(v3.w), a3);
    }
    a[0] = a0; a[1] = a1; a[2] = a2; a[3] = a3;
}

__device__ __forceinline__ void spmm_full_body(
        int blk0, int t,
        const int* __restrict__ rp_s, const int2* __restrict__ pr_s,
        const ushort* __restrict__ xs, ushort* ys,
        const int* __restrict__ rp_e, const int2* __restrict__ pr_e,
        const ushort* __restrict__ xe, ushort* ye,
        const int* __restrict__ rp_k, const int2* __restrict__ pr_k,
        const ushort* __restrict__ xk, ushort* yk) {
    int w = (blk0 * 256 + t) >> 4;
    int l = t & 15;
    const int* rp; const int2* pr; const ushort* x; ushort* y; int r;
    if (w < S_N) { rp = rp_s; pr = pr_s; x = xs; y = ys; r = w; }
    else if (w < S_N + E_N) { rp = rp_e; pr = pr_e; x = xe; y = ye; r = w - S_N; }
    else if (w < S_N + E_N + K_N) { rp = rp_k; pr = pr_k; x = xk; y = yk; r = w - S_N - E_N; }
    else return;
    float a[4];
    spmm_row_compute(rp, pr, x, r, l, a);
    ushort4 o;
    o.x = f2b(a[0]); o.y = f2b(a[1]); o.z = f2b(a[2]); o.w = f2b(a[3]);
    *(ushort4*)&y[r * 64 + l * 4] = o;
}

__device__ __forceinline__ void gather_accb_body(
        int i, const int* __restrict__ sid, const int* __restrict__ eid,
        const ushort* __restrict__ src_s, const ushort* __restrict__ src_e,
        const ushort* __restrict__ src_k,
        float* bacc_s, float* bacc_e, float* kacc) {
    const int BD = B_N * 64;
    if (i < BD) {
        int b = i >> 6, d = i & 63;
        bacc_s[i] += b2f(src_s[(long)sid[b] * 64 + d]);
    } else if (i < 2 * BD) {
        int ii = i - BD; int b = ii >> 6, d = ii & 63;
        bacc_e[ii] += b2f(src_e[(long)eid[b] * 64 + d]);
    } else if (i < 2 * BD + K_N * 64) {
        int ii = i - 2 * BD;
        kacc[ii] += b2f(src_k[ii]);
    }
}

// layer-1: full-table spmm only
__global__ void spmm_l1(const int* __restrict__ rp_s, const int2* __restrict__ pr_s,
                        const ushort* __restrict__ xs, ushort* ys,
                        const int* __restrict__ rp_e, const int2* __restrict__ pr_e,
                        const ushort* __restrict__ xe, ushort* ye,
                        const int* __restrict__ rp_k, const int2* __restrict__ pr_k,
                        const ushort* __restrict__ xk, ushort* yk) {
    spmm_full_body(blockIdx.x, threadIdx.x, rp_s, pr_s, xs, ys,
                   rp_e, pr_e, xe, ye, rp_k, pr_k, xk, yk);
}

// layer-2: full-table spmm (bufA->bufB) fused with gather_accb(bufA)
__global__ void spmm_l2_fused(const int* __restrict__ rp_s, const int2* __restrict__ pr_s,
                              const ushort* __restrict__ xs, ushort* ys,
                              const int* __restrict__ rp_e, const int2* __restrict__ pr_e,
                              const ushort* __restrict__ xe, ushort* ye,
                              const int* __restrict__ rp_k, const int2* __restrict__ pr_k,
                              const ushort* __restrict__ xk, ushort* yk,
                              const int* __restrict__ sid, const int* __restrict__ eid,
                              float* bacc_s, float* bacc_e, float* kacc) {
    int blk = blockIdx.x;
    if (blk < FULLB) {
        spmm_full_body(blk, threadIdx.x, rp_s, pr_s, xs, ys,
                       rp_e, pr_e, xe, ye, rp_k, pr_k, xk, yk);
    } else {
        int i = (blk - FULLB) * 256 + threadIdx.x;
        gather_accb_body(i, sid, eid, xs, xe, xk, bacc_s, bacc_e, kacc);
    }
}

// layer-3: batch-rows spmm (bufB->c3) + full K, fused with gather_accb(bufB)
__global__ void spmm_l3_fused(const int* __restrict__ sid, const int* __restrict__ eid,
                              const int* __restrict__ rp_s, const int2* __restrict__ pr_s,
                              const ushort* __restrict__ xs, ushort* c3s,
                              const int* __restrict__ rp_e, const int2* __restrict__ pr_e,
                              const ushort* __restrict__ xe, ushort* c3e,
                              const int* __restrict__ rp_k, const int2* __restrict__ pr_k,
                              const ushort* __restrict__ xk, ushort* yk,
                              float* bacc_s, float* bacc_e, float* kacc) {
    int blk = blockIdx.x;
    int t = threadIdx.x;
    if (blk < LASTB) {
        int w = (blk * 256 + t) >> 4;
        int l = t & 15;
        const int* rp; const int2* pr; const ushort* x; ushort* y; int r; int orow;
        if (w < B_N) { rp = rp_s; pr = pr_s; x = xs; y = c3s; r = sid[w]; orow = w; }
        else if (w < 2 * B_N) {
            int b = w - B_N;
            rp = rp_e; pr = pr_e; x = xe; y = c3e; r = eid[b]; orow = b;
        } else if (w < 2 * B_N + K_N) {
            r = w - 2 * B_N;
            rp = rp_k; pr = pr_k; x = xk; y = yk; orow = r;
        } else return;
        float a[4];
        spmm_row_compute(rp, pr, x, r, l, a);
        ushort4 o;
        o.x = f2b(a[0]); o.y = f2b(a[1]); o.z = f2b(a[2]); o.w = f2b(a[3]);
        *(ushort4*)&y[orow * 64 + l * 4] = o;
    } else {
        int i = (blk - LASTB) * 256 + t;
        gather_accb_body(i, sid, eid, xs, xe, xk, bacc_s, bacc_e, kacc);
    }
}

// =============================================================== post kernel
// fuses dense_mm | know_mm | disc (all depend only on layer-3 outputs)
__global__ void post_kernel(const float* __restrict__ bacc_s, const ushort* __restrict__ c3_s,
                            const float* __restrict__ bacc_e, const ushort* __restrict__ c3_e,
                            const float* __restrict__ W_stu, const float* __restrict__ b_stu,
                            const float* __restrict__ W_exer, const float* __restrict__ b_exer,
                            __hip_bfloat16* st_b, __hip_bfloat16* df_b,
                            const float* __restrict__ kacc, const ushort* __restrict__ cur3_k,
                            const float* __restrict__ W_know, const float* __restrict__ b_know,
                            float* out_kn_f32, __hip_bfloat16* kn_b,
                            const float* __restrict__ W_disc, const float* __restrict__ b_disc,
                            float* out_disc) {
    int blk = blockIdx.x;
    int t = threadIdx.x;
    if (blk < NDENSE) {
        int which = blk >> 13;                 // 8192 blocks each
        int local = blk & 8191;
        const float* bacc = which ? bacc_e : bacc_s;
        const ushort* c3 = which ? c3_e : c3_s;
        const float* W = which ? W_exer : W_stu;
        const float* bias = which ? b_exer : b_stu;
        __hip_bfloat16* out = which ? df_b : st_b;
        int r0 = local * 2;
        __shared__ float X[2][64];
        if (t < 128) {
            int lr = t >> 6, d = t & 63; int b = r0 + lr;
            X[lr][d] = 0.25f * (bacc[(long)b * 64 + d] + b2f(c3[(long)b * 64 + d]));
        }
        __syncthreads();
        int lr = t >> 7, f = t & 127;
        float acc = bias[f];
        for (int d = 0; d < 64; d++) acc += X[lr][d] * W[d * 128 + f];
        acc = acc > 0.f ? acc : 0.1f * acc;
        out[(long)(r0 + lr) * 128 + f] = __float2bfloat16(acc);
    } else if (blk < NDENSE + NKNOW) {
        int r0 = (blk - NDENSE) * 2;
        __shared__ float X[2][64];
        if (t < 128) {
            int lr = t >> 6, d = t & 63; int r = r0 + lr;
            X[lr][d] = (r < K_N) ? 0.25f * (kacc[r * 64 + d] + b2f(cur3_k[r * 64 + d])) : 0.f;
        }
        __syncthreads();
        int lr = t >> 7, f = t & 127; int r = r0 + lr;
        float acc = b_know[f];
        for (int d = 0; d < 64; d++) acc += X[lr][d] * W_know[d * 128 + f];
        acc = acc > 0.f ? acc : 0.1f * acc;
        if (r < K_N) {
            out_kn_f32[(long)r * 128 + f] = acc;
            kn_b[(long)r * 128 + f] = __float2bfloat16(acc);
        } else {
            kn_b[(long)r * 128 + f] = __float2bfloat16(0.f);
        }
    } else {
        int w = ((blk - NDENSE - NKNOW) * 256 + t) >> 6;
        int d = t & 63;
        if (w >= B_N) return;
        float x = 0.25f * (bacc_e[(long)w * 64 + d] + b2f(c3_e[(long)w * 64 + d])) * W_disc[d];
        for (int off = 32; off > 0; off >>= 1) x += __shfl_down(x, off, 64);
        if (d == 0) {
            float z = x + b_disc[0];
            out_disc[w] = 1.f / (1.f + expf(-z));
        }
    }
}

// --------------------------------------------- big GEMM: [B,128] @ [128,1024p]^T
__global__ void big_mm(const __hip_bfloat16* __restrict__ st, const __hip_bfloat16* __restrict__ df,
                       const __hip_bfloat16* __restrict__ kn,
                       float* __restrict__ out0, float* __restrict__ out1) {
    const ushort* X = (const ushort*)(blockIdx.z ? df : st);
    const ushort* Kn = (const ushort*)kn;
    float* out = blockIdx.z ? out1 : out0;
    int wv = threadIdx.x >> 6;
    int lane = threadIdx.x & 63;
    int m_blk = blockIdx.y * 64 + (wv >> 1) * 32;
    int n_blk = blockIdx.x * 64 + (wv & 1) * 32;
    int q = lane >> 4, l16 = lane & 15;
    f4 acc00 = {0.f, 0.f, 0.f, 0.f}, acc01 = acc00, acc10 = acc00, acc11 = acc00;
    for (int s = 0; s < 4; s++) {
        int kofs = s * 32 + q * 8;
        sh8 a0 = *(const sh8*)&X[(long)(m_blk + l16) * 128 + kofs];
        sh8 a1 = *(const sh8*)&X[(long)(m_blk + 16 + l16) * 128 + kofs];
        sh8 b0 = *(const sh8*)&Kn[(long)(n_blk + l16) * 128 + kofs];
        sh8 b1 = *(const sh8*)&Kn[(long)(n_blk + 16 + l16) * 128 + kofs];
        acc00 = __builtin_amdgcn_mfma_f32_16x16x32_bf16(a0, b0, acc00, 0, 0, 0);
        acc01 = __builtin_amdgcn_mfma_f32_16x16x32_bf16(a0, b1, acc01, 0, 0, 0);
        acc10 = __builtin_amdgcn_mfma_f32_16x16x32_bf16(a1, b0, acc10, 0, 0, 0);
        acc11 = __builtin_amdgcn_mfma_f32_16x16x32_bf16(a1, b1, acc11, 0, 0, 0);
    }
    for (int r = 0; r < 4; r++) {
        int row0 = m_blk + q * 4 + r;
        int row1 = m_blk + 16 + q * 4 + r;
        int col0 = n_blk + l16;
        int col1 = n_blk + 16 + l16;
        if (col0 < K_N) {
            out[(long)row0 * K_N + col0] = acc00[r];
            out[(long)row1 * K_N + col0] = acc10[r];
        }
        if (col1 < K_N) {
            out[(long)row0 * K_N + col1] = acc01[r];
            out[(long)row1 * K_N + col1] = acc11[r];
        }
    }
}

// ---------------------------------------------------------------------------
extern "C" void kernel_launch(void* const* d_in, const int* in_sizes, int n_in,
                              void* d_out, int out_size, void* d_ws, size_t ws_size,
                              hipStream_t stream) {
    const int* sid = (const int*)d_in[0];
    const int* eid = (const int*)d_in[1];
    // d_in[2] q_mask unused
    const float* stu_emb = (const float*)d_in[3];
    const float* exer_emb = (const float*)d_in[4];
    const float* know_emb = (const float*)d_in[5];
    const float* impact_emb = (const float*)d_in[6];
    const int* s_rows = (const int*)d_in[7];
    const int* s_cols = (const int*)d_in[8];
    const float* s_vals = (const float*)d_in[9];
    const int* e_rows = (const int*)d_in[10];
    const int* e_cols = (const int*)d_in[11];
    const float* e_vals = (const float*)d_in[12];
    const int* k_rows = (const int*)d_in[13];
    const int* k_cols = (const int*)d_in[14];
    const float* k_vals = (const float*)d_in[15];
    const float* W_stu = (const float*)d_in[16];
    const float* b_stu = (const float*)d_in[17];
    const float* W_exer = (const float*)d_in[18];
    const float* b_exer = (const float*)d_in[19];
    const float* W_know = (const float*)d_in[20];
    const float* b_know = (const float*)d_in[21];
    const float* W_disc = (const float*)d_in[22];
    const float* b_disc = (const float*)d_in[23];

    float* out = (float*)d_out;
    float* out_st = out;                       // [B,1000]
    float* out_df = out + 16384000;            // [B,1000]
    float* out_disc = out + 32768000;          // [B,1]
    float* out_kn = out + 32784384;            // [1000,128]
    float* out_imp = out + 32912384;           // [B,64]

    char* p = (char*)d_ws;
    auto alloc = [&](size_t bytes) -> char* {
        char* r = p;
        p += (bytes + 255) & ~(size_t)255;
        return r;
    };
    ushort* xb_s = (ushort*)alloc((size_t)S_N * 64 * 2);   // bf16 embeddings
    ushort* xb_e = (ushort*)alloc((size_t)E_N * 64 * 2);
    ushort* xb_k = (ushort*)alloc((size_t)K_N * 64 * 2);
    ushort* bufA_s = (ushort*)alloc((size_t)S_N * 64 * 2);
    ushort* bufB_s = (ushort*)alloc((size_t)S_N * 64 * 2);
    ushort* bufA_e = (ushort*)alloc((size_t)E_N * 64 * 2);
    ushort* bufB_e = (ushort*)alloc((size_t)E_N * 64 * 2);
    ushort* bufA_k = (ushort*)alloc((size_t)K_N * 64 * 2);
    ushort* bufB_k = (ushort*)alloc((size_t)K_N * 64 * 2);
    ushort* c3s = (ushort*)alloc((size_t)B_N * 64 * 2);    // layer-3 per-batch rows
    ushort* c3e = (ushort*)alloc((size_t)B_N * 64 * 2);
    float* bacc_s = (float*)alloc((size_t)B_N * 64 * 4);
    float* bacc_e = (float*)alloc((size_t)B_N * 64 * 4);
    float* kacc = (float*)alloc((size_t)K_N * 64 * 4);
    __hip_bfloat16* st_b = (__hip_bfloat16*)alloc((size_t)B_N * 128 * 2);
    __hip_bfloat16* df_b = (__hip_bfloat16*)alloc((size_t)B_N * 128 * 2);
    __hip_bfloat16* kn_b = (__hip_bfloat16*)alloc((size_t)1024 * 128 * 2);
    // bucket totals + reservation cursors (zeroed together)
    int* bcnt_tot = (int*)alloc((size_t)2 * NB_TOT * 4);
    int* rsv = bcnt_tot + NB_TOT;
    int* rp_s = (int*)alloc((size_t)(S_N + 1) * 4);
    int* rp_e = (int*)alloc((size_t)(E_N + 1) * 4);
    int* rp_k = (int*)alloc((size_t)(K_N + 1) * 4);
    int2* stg_s = (int2*)alloc((size_t)NNZ_S * 8);
    int2* stg_e = (int2*)alloc((size_t)NNZ_E * 8);
    int2* stg_k = (int2*)alloc((size_t)NNZ_K * 8);
    int2* pr_s = (int2*)alloc((size_t)NNZ_S * 8);
    int2* pr_e = (int2*)alloc((size_t)NNZ_E * 8);
    int2* pr_k = (int2*)alloc((size_t)NNZ_K * 8);

    // 1) zero counters
    hipMemsetAsync(bcnt_tot, 0, (size_t)2 * NB_TOT * 4, stream);
    // 2) fused: convert + gather_init + bucket_count + impact
    pre_kernel<<<NCONV + NGATH + SB_TOT + NIMP, 256, 0, stream>>>(
        stu_emb, exer_emb, know_emb, xb_s, xb_e, xb_k,
        sid, eid, bacc_s, bacc_e, kacc,
        s_rows, e_rows, k_rows, bcnt_tot, impact_emb, out_imp);
    // 3) stage1 (inline segment scan)
    stage1_bin<<<SB_TOT, 256, 0, stream>>>(
        s_rows, s_cols, s_vals, e_rows, e_cols, e_vals, k_rows, k_cols, k_vals,
        bcnt_tot, rsv, stg_s, stg_e, stg_k);
    // 4) stage2 (inline prefix, writes rp directly)
    stage2_place<<<NB_TOT, 256, 0, stream>>>(bcnt_tot,
                                             stg_s, pr_s, rp_s,
                                             stg_e, pr_e, rp_e,
                                             stg_k, pr_k, rp_k);
    // 5) layer-1 spmm
    spmm_l1<<<FULLB, 256, 0, stream>>>(rp_s, pr_s, xb_s, bufA_s,
                                       rp_e, pr_e, xb_e, bufA_e,
                                       rp_k, pr_k, xb_k, bufA_k);
    // 6) layer-2 spmm + gather_accb(bufA)
    spmm_l2_fused<<<FULLB + NGATH, 256, 0, stream>>>(
        rp_s, pr_s, bufA_s, bufB_s,
        rp_e, pr_e, bufA_e, bufB_e,
        rp_k, pr_k, bufA_k, bufB_k,
        sid, eid, bacc_s, bacc_e, kacc);
    // 7) layer-3 batched spmm + gather_accb(bufB)
    spmm_l3_fused<<<LASTB + NGATH, 256, 0, stream>>>(
        sid, eid,
        rp_s, pr_s, bufB_s, c3s,
        rp_e, pr_e, bufB_e, c3e,
        rp_k, pr_k, bufB_k, bufA_k,
        bacc_s, bacc_e, kacc);
    // 8) fused dense stage
    post_kernel<<<NDENSE + NKNOW + NDISC, 256, 0, stream>>>(
        bacc_s, c3s, bacc_e, c3e, W_stu, b_stu, W_exer, b_exer, st_b, df_b,
        kacc, bufA_k, W_know, b_know, out_kn, kn_b,
        W_disc, b_disc, out_disc);
    // 9) big GEMMs
    big_mm<<<dim3(16, B_N / 64, 2), 256, 0, stream>>>(st_b, df_b, kn_b, out_st, out_df);
}